// Round 1
// baseline (703.634 us; speedup 1.0000x reference)
//
#include <hip/hip_runtime.h>

#define NN 100000
#define NE 1600000
constexpr int KDIM = 128;

// ---------------- preprocessing ----------------

__global__ __launch_bounds__(256) void k_zero(int* p, int n) {
  int i = blockIdx.x * 256 + threadIdx.x;
  if (i < n) p[i] = 0;
}

__global__ __launch_bounds__(256) void k_hist(const int* __restrict__ col,
                                              int* __restrict__ counts, int ne) {
  int i = blockIdx.x * 256 + threadIdx.x;
  if (i < ne) atomicAdd(&counts[col[i]], 1);
}

__global__ __launch_bounds__(256) void k_dinv(const int* __restrict__ counts,
                                              float* __restrict__ dinv, int n) {
  int i = blockIdx.x * 256 + threadIdx.x;
  if (i < n) dinv[i] = rsqrtf((float)(counts[i] + 1));  // +1 self loop
}

// exclusive scan of counts -> rowptr (3 kernels)
__global__ __launch_bounds__(256) void k_scan1(const int* __restrict__ counts,
                                               int* __restrict__ rowptr,
                                               int* __restrict__ bsum, int n) {
  __shared__ int sd[256];
  int t = threadIdx.x;
  int base = blockIdx.x * 1024 + t * 4;
  int v0 = 0, v1 = 0, v2 = 0, v3 = 0;
  if (base + 0 < n) v0 = counts[base + 0];
  if (base + 1 < n) v1 = counts[base + 1];
  if (base + 2 < n) v2 = counts[base + 2];
  if (base + 3 < n) v3 = counts[base + 3];
  int s = v0 + v1 + v2 + v3;
  sd[t] = s;
  __syncthreads();
  for (int off = 1; off < 256; off <<= 1) {
    int x = (t >= off) ? sd[t - off] : 0;
    __syncthreads();
    sd[t] += x;
    __syncthreads();
  }
  int run = sd[t] - s;  // exclusive prefix of this thread's chunk
  if (base + 0 < n) rowptr[base + 0] = run;
  run += v0;
  if (base + 1 < n) rowptr[base + 1] = run;
  run += v1;
  if (base + 2 < n) rowptr[base + 2] = run;
  run += v2;
  if (base + 3 < n) rowptr[base + 3] = run;
  if (t == 255) bsum[blockIdx.x] = sd[255];
}

__global__ void k_scan2(int* __restrict__ bsum, int nb) {
  __shared__ int sd[256];
  int t = threadIdx.x;
  int v = (t < nb) ? bsum[t] : 0;
  sd[t] = v;
  __syncthreads();
  for (int off = 1; off < 256; off <<= 1) {
    int x = (t >= off) ? sd[t - off] : 0;
    __syncthreads();
    sd[t] += x;
    __syncthreads();
  }
  if (t < nb) bsum[t] = sd[t] - v;  // exclusive, in place
}

__global__ __launch_bounds__(256) void k_scan3(int* __restrict__ rowptr,
                                               const int* __restrict__ bsum,
                                               int* __restrict__ fill, int n, int ne) {
  int i = blockIdx.x * 256 + threadIdx.x;
  if (i < n) {
    rowptr[i] += bsum[i >> 10];
    fill[i] = 0;
  }
  if (i == n) rowptr[n] = ne;
}

__global__ __launch_bounds__(256) void k_scatter(const int* __restrict__ row,
                                                 const int* __restrict__ col,
                                                 const int* __restrict__ rowptr,
                                                 int* __restrict__ fill,
                                                 int* __restrict__ srcs, int ne) {
  int i = blockIdx.x * 256 + threadIdx.x;
  if (i < ne) {
    int c = col[i];
    int p = rowptr[c] + atomicAdd(&fill[c], 1);
    srcs[p] = row[i];
  }
}

// ---------------- GEMM: Y[r,:] = (A[r,:] @ W) * dinv[r] ----------------
// A is [M,128] row-major, W is [128,BN] row-major, Y is [M,BN].
template <int BN>
__global__ __launch_bounds__(256, 2) void k_gemm_scale(const float* __restrict__ A,
                                                       const float* __restrict__ W,
                                                       const float* __restrict__ dinv,
                                                       float* __restrict__ Y, int M) {
  constexpr int BM = 128;
  constexpr int BK = 8;
  constexpr int TX = BN / 8;   // threads along cols (each does 8 cols)
  constexpr int TY = 256 / TX; // threads along rows
  constexpr int MR = BM / TY;  // rows per thread
  constexpr int HR = MR / 2;

  __shared__ float As[BK][BM];
  __shared__ float Bs[BK][BN];

  const int t = threadIdx.x;
  const int rowbase = blockIdx.x * BM;
  const int tx = t % TX;
  const int ty = t / TX;

  float acc[MR][8];
#pragma unroll
  for (int i = 0; i < MR; ++i)
#pragma unroll
    for (int j = 0; j < 8; ++j) acc[i][j] = 0.f;

  const int arow = t >> 1;
  const int akq = (t & 1) * 4;
  const bool avalid = (rowbase + arow) < M;
  const float* aptr = A + (size_t)(rowbase + arow) * KDIM + akq;

  constexpr int BQ = BN / 4;
  const int bk = t / BQ;
  const int bc = (t % BQ) * 4;
  const float* bptr = W + (size_t)(bk < BK ? bk : 0) * BN + bc;

  for (int k0 = 0; k0 < KDIM; k0 += BK) {
    float4 av = make_float4(0.f, 0.f, 0.f, 0.f);
    if (avalid) av = *(const float4*)(aptr + k0);
    float4 bv = make_float4(0.f, 0.f, 0.f, 0.f);
    if (bk < BK) bv = *(const float4*)(bptr + (size_t)k0 * BN);
    __syncthreads();
    As[akq + 0][arow] = av.x;
    As[akq + 1][arow] = av.y;
    As[akq + 2][arow] = av.z;
    As[akq + 3][arow] = av.w;
    if (bk < BK) *(float4*)&Bs[bk][bc] = bv;
    __syncthreads();
#pragma unroll
    for (int k = 0; k < BK; ++k) {
      float a[MR], b[8];
#pragma unroll
      for (int i = 0; i < HR; ++i) {
        a[i] = As[k][ty * HR + i];
        a[HR + i] = As[k][64 + ty * HR + i];
      }
#pragma unroll
      for (int j = 0; j < 4; ++j) {
        b[j] = Bs[k][tx * 4 + j];
        b[4 + j] = Bs[k][BN / 2 + tx * 4 + j];
      }
#pragma unroll
      for (int i = 0; i < MR; ++i)
#pragma unroll
        for (int j = 0; j < 8; ++j) acc[i][j] += a[i] * b[j];
    }
  }

#pragma unroll
  for (int i = 0; i < MR; ++i) {
    int rr = (i < HR) ? (ty * HR + i) : (64 + ty * HR + (i - HR));
    int r = rowbase + rr;
    if (r < M) {
      float dv = dinv[r];
      float* yrow = Y + (size_t)r * BN;
      float4 o0 = make_float4(acc[i][0] * dv, acc[i][1] * dv, acc[i][2] * dv, acc[i][3] * dv);
      float4 o1 = make_float4(acc[i][4] * dv, acc[i][5] * dv, acc[i][6] * dv, acc[i][7] * dv);
      *(float4*)(yrow + tx * 4) = o0;
      *(float4*)(yrow + BN / 2 + tx * 4) = o1;
    }
  }
}

// ---------------- aggregation: Out[c,:] = relu?(dinv[c]*(y[c,:]+sum y[src,:]) + b) ----
template <int D, bool RELU>
__global__ __launch_bounds__(256) void k_agg(const float* __restrict__ Y,
                                             const int* __restrict__ rowptr,
                                             const int* __restrict__ srcs,
                                             const float* __restrict__ dinv,
                                             const float* __restrict__ bias,
                                             float* __restrict__ Out, int n) {
  const int wave = threadIdx.x >> 6;
  const int lane = threadIdx.x & 63;
  const int node = blockIdx.x * 4 + wave;
  if (node >= n) return;
  const int jb = rowptr[node];
  const int je = rowptr[node + 1];
  if constexpr (D == 128) {
    float2 acc = *(const float2*)(Y + (size_t)node * 128 + lane * 2);  // self loop
    int j = jb;
    for (; j + 2 <= je; j += 2) {
      int s0 = srcs[j], s1 = srcs[j + 1];
      float2 v0 = *(const float2*)(Y + (size_t)s0 * 128 + lane * 2);
      float2 v1 = *(const float2*)(Y + (size_t)s1 * 128 + lane * 2);
      acc.x += v0.x + v1.x;
      acc.y += v0.y + v1.y;
    }
    if (j < je) {
      int s = srcs[j];
      float2 v = *(const float2*)(Y + (size_t)s * 128 + lane * 2);
      acc.x += v.x;
      acc.y += v.y;
    }
    const float dv = dinv[node];
    float2 bb = *(const float2*)(bias + lane * 2);
    float ox = fmaf(acc.x, dv, bb.x);
    float oy = fmaf(acc.y, dv, bb.y);
    if (RELU) {
      ox = fmaxf(ox, 0.f);
      oy = fmaxf(oy, 0.f);
    }
    *(float2*)(Out + (size_t)node * 128 + lane * 2) = make_float2(ox, oy);
  } else {
    float acc = Y[(size_t)node * 64 + lane];
    for (int j = jb; j < je; ++j) {
      int s = srcs[j];
      acc += Y[(size_t)s * 64 + lane];
    }
    float o = fmaf(acc, dinv[node], bias[lane]);
    if (RELU) o = fmaxf(o, 0.f);
    Out[(size_t)node * 64 + lane] = o;
  }
}

// ---------------- launch ----------------

extern "C" void kernel_launch(void* const* d_in, const int* in_sizes, int n_in,
                              void* d_out, int out_size, void* d_ws, size_t ws_size,
                              hipStream_t stream) {
  const float* x = (const float*)d_in[0];
  const int* ei = (const int*)d_in[1];
  const float* W1 = (const float*)d_in[2];
  const float* b1 = (const float*)d_in[3];
  const float* W2 = (const float*)d_in[4];
  const float* b2 = (const float*)d_in[5];
  const float* W3 = (const float*)d_in[6];
  const float* b3 = (const float*)d_in[7];
  float* out = (float*)d_out;

  const int* erow = ei;       // edge_index[0] = sources
  const int* ecol = ei + NE;  // edge_index[1] = targets

  char* w = (char*)d_ws;
  auto alloc = [&](size_t b) {
    char* p = w;
    w += (b + 255) & ~(size_t)255;
    return (void*)p;
  };
  int* counts = (int*)alloc((size_t)NN * 4);
  float* dinv = (float*)alloc((size_t)NN * 4);
  int* rowptr = (int*)alloc((size_t)(NN + 1) * 4);
  int* fill = (int*)alloc((size_t)NN * 4);
  int* bsum = (int*)alloc(1024);
  int* srcs = (int*)alloc((size_t)NE * 4);
  float* ybuf = (float*)alloc((size_t)NN * 128 * 4);
  float* hbuf = (float*)alloc((size_t)NN * 128 * 4);

  const int nbN = (NN + 255) / 256;    // 391
  const int nbE = (NE + 255) / 256;    // 6250
  const int nb1 = (NN + 1023) / 1024;  // 98

  k_zero<<<nbN, 256, 0, stream>>>(counts, NN);
  k_hist<<<nbE, 256, 0, stream>>>(ecol, counts, NE);
  k_dinv<<<nbN, 256, 0, stream>>>(counts, dinv, NN);
  k_scan1<<<nb1, 256, 0, stream>>>(counts, rowptr, bsum, NN);
  k_scan2<<<1, 256, 0, stream>>>(bsum, nb1);
  k_scan3<<<nbN, 256, 0, stream>>>(rowptr, bsum, fill, NN, NE);
  k_scatter<<<nbE, 256, 0, stream>>>(erow, ecol, rowptr, fill, srcs, NE);

  const int nbG = (NN + 127) / 128;  // 782
  const int nbA = (NN + 3) / 4;      // 25000

  // Layer 1: x -> hbuf
  k_gemm_scale<128><<<nbG, 256, 0, stream>>>(x, W1, dinv, ybuf, NN);
  k_agg<128, true><<<nbA, 256, 0, stream>>>(ybuf, rowptr, srcs, dinv, b1, hbuf, NN);
  // Layer 2: hbuf -> hbuf (via ybuf)
  k_gemm_scale<128><<<nbG, 256, 0, stream>>>(hbuf, W2, dinv, ybuf, NN);
  k_agg<128, true><<<nbA, 256, 0, stream>>>(ybuf, rowptr, srcs, dinv, b2, hbuf, NN);
  // Layer 3: hbuf -> out
  k_gemm_scale<64><<<nbG, 256, 0, stream>>>(hbuf, W3, dinv, ybuf, NN);
  k_agg<64, false><<<nbA, 256, 0, stream>>>(ybuf, rowptr, srcs, dinv, b3, out, NN);
}

// Round 3
// 615.690 us; speedup vs baseline: 1.1428x; 1.1428x over previous
//
#include <hip/hip_runtime.h>

#define NN 100000
#define NE 1600000
constexpr int KDIM = 128;

// ---------------- preprocessing ----------------

__global__ __launch_bounds__(256) void k_zero(int* p, int n) {
  int i = blockIdx.x * 256 + threadIdx.x;
  if (i < n) p[i] = 0;
}

__global__ __launch_bounds__(256) void k_hist(const int* __restrict__ col,
                                              int* __restrict__ counts, int ne) {
  int i = blockIdx.x * 256 + threadIdx.x;
  if (i < ne) atomicAdd(&counts[col[i]], 1);
}

__global__ __launch_bounds__(256) void k_dinv(const int* __restrict__ counts,
                                              float* __restrict__ dinv, int n) {
  int i = blockIdx.x * 256 + threadIdx.x;
  if (i < n) dinv[i] = rsqrtf((float)(counts[i] + 1));  // +1 self loop
}

// exclusive scan of counts -> rowptr (3 kernels)
__global__ __launch_bounds__(256) void k_scan1(const int* __restrict__ counts,
                                               int* __restrict__ rowptr,
                                               int* __restrict__ bsum, int n) {
  __shared__ int sd[256];
  int t = threadIdx.x;
  int base = blockIdx.x * 1024 + t * 4;
  int v0 = 0, v1 = 0, v2 = 0, v3 = 0;
  if (base + 0 < n) v0 = counts[base + 0];
  if (base + 1 < n) v1 = counts[base + 1];
  if (base + 2 < n) v2 = counts[base + 2];
  if (base + 3 < n) v3 = counts[base + 3];
  int s = v0 + v1 + v2 + v3;
  sd[t] = s;
  __syncthreads();
  for (int off = 1; off < 256; off <<= 1) {
    int x = (t >= off) ? sd[t - off] : 0;
    __syncthreads();
    sd[t] += x;
    __syncthreads();
  }
  int run = sd[t] - s;  // exclusive prefix of this thread's chunk
  if (base + 0 < n) rowptr[base + 0] = run;
  run += v0;
  if (base + 1 < n) rowptr[base + 1] = run;
  run += v1;
  if (base + 2 < n) rowptr[base + 2] = run;
  run += v2;
  if (base + 3 < n) rowptr[base + 3] = run;
  if (t == 255) bsum[blockIdx.x] = sd[255];
}

__global__ void k_scan2(int* __restrict__ bsum, int nb) {
  __shared__ int sd[256];
  int t = threadIdx.x;
  int v = (t < nb) ? bsum[t] : 0;
  sd[t] = v;
  __syncthreads();
  for (int off = 1; off < 256; off <<= 1) {
    int x = (t >= off) ? sd[t - off] : 0;
    __syncthreads();
    sd[t] += x;
    __syncthreads();
  }
  if (t < nb) bsum[t] = sd[t] - v;  // exclusive, in place
}

__global__ __launch_bounds__(256) void k_scan3(int* __restrict__ rowptr,
                                               const int* __restrict__ bsum,
                                               int* __restrict__ fill, int n, int ne) {
  int i = blockIdx.x * 256 + threadIdx.x;
  if (i < n) {
    rowptr[i] += bsum[i >> 10];
    fill[i] = 0;
  }
  if (i == n) rowptr[n] = ne;
}

__global__ __launch_bounds__(256) void k_scatter(const int* __restrict__ row,
                                                 const int* __restrict__ col,
                                                 const int* __restrict__ rowptr,
                                                 int* __restrict__ fill,
                                                 int* __restrict__ srcs, int ne) {
  int i = blockIdx.x * 256 + threadIdx.x;
  if (i < ne) {
    int c = col[i];
    int p = rowptr[c] + atomicAdd(&fill[c], 1);
    srcs[p] = row[i];
  }
}

// ---------------- GEMM: Y[r,:] = (A[r,:] @ W) * dinv[r] ----------------
// A is [M,128] row-major, W is [128,BN] row-major, Y is [M,BN].
template <int BN>
__global__ __launch_bounds__(256, 2) void k_gemm_scale(const float* __restrict__ A,
                                                       const float* __restrict__ W,
                                                       const float* __restrict__ dinv,
                                                       float* __restrict__ Y, int M) {
  constexpr int BM = 128;
  constexpr int BK = 8;
  constexpr int TX = BN / 8;   // threads along cols (each does 8 cols)
  constexpr int TY = 256 / TX; // threads along rows
  constexpr int MR = BM / TY;  // rows per thread
  constexpr int HR = MR / 2;

  __shared__ float As[BK][BM];
  __shared__ float Bs[BK][BN];

  const int t = threadIdx.x;
  const int rowbase = blockIdx.x * BM;
  const int tx = t % TX;
  const int ty = t / TX;

  float acc[MR][8];
#pragma unroll
  for (int i = 0; i < MR; ++i)
#pragma unroll
    for (int j = 0; j < 8; ++j) acc[i][j] = 0.f;

  const int arow = t >> 1;
  const int akq = (t & 1) * 4;
  const bool avalid = (rowbase + arow) < M;
  const float* aptr = A + (size_t)(rowbase + arow) * KDIM + akq;

  constexpr int BQ = BN / 4;
  const int bk = t / BQ;
  const int bc = (t % BQ) * 4;
  const float* bptr = W + (size_t)(bk < BK ? bk : 0) * BN + bc;

  for (int k0 = 0; k0 < KDIM; k0 += BK) {
    float4 av = make_float4(0.f, 0.f, 0.f, 0.f);
    if (avalid) av = *(const float4*)(aptr + k0);
    float4 bv = make_float4(0.f, 0.f, 0.f, 0.f);
    if (bk < BK) bv = *(const float4*)(bptr + (size_t)k0 * BN);
    __syncthreads();
    As[akq + 0][arow] = av.x;
    As[akq + 1][arow] = av.y;
    As[akq + 2][arow] = av.z;
    As[akq + 3][arow] = av.w;
    if (bk < BK) *(float4*)&Bs[bk][bc] = bv;
    __syncthreads();
#pragma unroll
    for (int k = 0; k < BK; ++k) {
      float a[MR], b[8];
#pragma unroll
      for (int i = 0; i < HR; ++i) {
        a[i] = As[k][ty * HR + i];
        a[HR + i] = As[k][64 + ty * HR + i];
      }
#pragma unroll
      for (int j = 0; j < 4; ++j) {
        b[j] = Bs[k][tx * 4 + j];
        b[4 + j] = Bs[k][BN / 2 + tx * 4 + j];
      }
#pragma unroll
      for (int i = 0; i < MR; ++i)
#pragma unroll
        for (int j = 0; j < 8; ++j) acc[i][j] += a[i] * b[j];
    }
  }

#pragma unroll
  for (int i = 0; i < MR; ++i) {
    int rr = (i < HR) ? (ty * HR + i) : (64 + ty * HR + (i - HR));
    int r = rowbase + rr;
    if (r < M) {
      float dv = dinv[r];
      float* yrow = Y + (size_t)r * BN;
      float4 o0 = make_float4(acc[i][0] * dv, acc[i][1] * dv, acc[i][2] * dv, acc[i][3] * dv);
      float4 o1 = make_float4(acc[i][4] * dv, acc[i][5] * dv, acc[i][6] * dv, acc[i][7] * dv);
      *(float4*)(yrow + tx * 4) = o0;
      *(float4*)(yrow + BN / 2 + tx * 4) = o1;
    }
  }
}

// ---------------- aggregation (latency-optimized, wave-uniform control flow) --
// All loop trip counts are wave-uniform (m is uniform per wave); every __shfl
// executes with ALL 64 lanes active. Tail edges are handled in ONE masked
// iteration using value selects (no divergent loop exits -> no reads from
// exec-masked shfl sources, which return 0 on CDNA).
template <bool RELU>
__global__ __launch_bounds__(256) void k_agg128(const float* __restrict__ Y,
                                                const int* __restrict__ rowptr,
                                                const int* __restrict__ srcs,
                                                const float* __restrict__ dinv,
                                                const float* __restrict__ bias,
                                                float* __restrict__ Out, int n) {
  const int wave = threadIdx.x >> 6;
  const int lane = threadIdx.x & 63;
  const int node = blockIdx.x * 4 + wave;
  if (node >= n) return;
  const int half = lane >> 5;  // which edge of the pair
  const int q = lane & 31;     // column quad: cols q*4..q*4+3
  const int jb = rowptr[node];
  const int je = rowptr[node + 1];

  float4 acc = make_float4(0.f, 0.f, 0.f, 0.f);
  if (half == 0) acc = *(const float4*)(Y + (size_t)node * 128 + q * 4);  // self loop

  for (int j0 = jb; j0 < je; j0 += 64) {
    const int m = min(64, je - j0);  // wave-uniform
    int idx = 0;
    if (lane < m) idx = srcs[j0 + lane];
    const int full = m & ~7;  // wave-uniform
    int eb = 0;
    for (; eb < full; eb += 8) {  // uniform trip count: no divergence
      const int e0 = eb + half;
      int s0 = __shfl(idx, e0);
      int s1 = __shfl(idx, e0 + 2);
      int s2 = __shfl(idx, e0 + 4);
      int s3 = __shfl(idx, e0 + 6);
      float4 v0 = *(const float4*)(Y + (size_t)s0 * 128 + q * 4);
      float4 v1 = *(const float4*)(Y + (size_t)s1 * 128 + q * 4);
      float4 v2 = *(const float4*)(Y + (size_t)s2 * 128 + q * 4);
      float4 v3 = *(const float4*)(Y + (size_t)s3 * 128 + q * 4);
      acc.x += (v0.x + v1.x) + (v2.x + v3.x);
      acc.y += (v0.y + v1.y) + (v2.y + v3.y);
      acc.z += (v0.z + v1.z) + (v2.z + v3.z);
      acc.w += (v0.w + v1.w) + (v2.w + v3.w);
    }
    if (eb < m) {  // wave-uniform condition: ONE masked tail iteration
      const int e0 = eb + half;
      int s0 = __shfl(idx, e0);
      int s1 = __shfl(idx, e0 + 2);
      int s2 = __shfl(idx, e0 + 4);
      int s3 = __shfl(idx, e0 + 6);  // sources all active; idx=0 if >= m
      float4 v0 = *(const float4*)(Y + (size_t)s0 * 128 + q * 4);
      float4 v1 = *(const float4*)(Y + (size_t)s1 * 128 + q * 4);
      float4 v2 = *(const float4*)(Y + (size_t)s2 * 128 + q * 4);
      float4 v3 = *(const float4*)(Y + (size_t)s3 * 128 + q * 4);
      const float m0 = (e0 < m) ? 1.f : 0.f;
      const float m1 = (e0 + 2 < m) ? 1.f : 0.f;
      const float m2 = (e0 + 4 < m) ? 1.f : 0.f;
      const float m3 = (e0 + 6 < m) ? 1.f : 0.f;
      acc.x += (m0 * v0.x + m1 * v1.x) + (m2 * v2.x + m3 * v3.x);
      acc.y += (m0 * v0.y + m1 * v1.y) + (m2 * v2.y + m3 * v3.y);
      acc.z += (m0 * v0.z + m1 * v1.z) + (m2 * v2.z + m3 * v3.z);
      acc.w += (m0 * v0.w + m1 * v1.w) + (m2 * v2.w + m3 * v3.w);
    }
  }

  // combine the two half-wave partial sums
  acc.x += __shfl_xor(acc.x, 32);
  acc.y += __shfl_xor(acc.y, 32);
  acc.z += __shfl_xor(acc.z, 32);
  acc.w += __shfl_xor(acc.w, 32);

  if (half == 0) {
    const float dv = dinv[node];
    float4 bb = *(const float4*)(bias + q * 4);
    float4 o;
    o.x = fmaf(acc.x, dv, bb.x);
    o.y = fmaf(acc.y, dv, bb.y);
    o.z = fmaf(acc.z, dv, bb.z);
    o.w = fmaf(acc.w, dv, bb.w);
    if (RELU) {
      o.x = fmaxf(o.x, 0.f);
      o.y = fmaxf(o.y, 0.f);
      o.z = fmaxf(o.z, 0.f);
      o.w = fmaxf(o.w, 0.f);
    }
    *(float4*)(Out + (size_t)node * 128 + q * 4) = o;
  }
}

// D=64: 4 edges per VMEM instr (16 lanes x float4 per row).
__global__ __launch_bounds__(256) void k_agg64(const float* __restrict__ Y,
                                               const int* __restrict__ rowptr,
                                               const int* __restrict__ srcs,
                                               const float* __restrict__ dinv,
                                               const float* __restrict__ bias,
                                               float* __restrict__ Out, int n) {
  const int wave = threadIdx.x >> 6;
  const int lane = threadIdx.x & 63;
  const int node = blockIdx.x * 4 + wave;
  if (node >= n) return;
  const int part = lane >> 4;  // which edge of the quad
  const int q = lane & 15;     // column quad: cols q*4..q*4+3
  const int jb = rowptr[node];
  const int je = rowptr[node + 1];

  float4 acc = make_float4(0.f, 0.f, 0.f, 0.f);
  if (part == 0) acc = *(const float4*)(Y + (size_t)node * 64 + q * 4);  // self loop

  for (int j0 = jb; j0 < je; j0 += 64) {
    const int m = min(64, je - j0);  // wave-uniform
    int idx = 0;
    if (lane < m) idx = srcs[j0 + lane];
    const int full = m & ~15;  // wave-uniform
    int eb = 0;
    for (; eb < full; eb += 16) {
      const int e0 = eb + part;
      int s0 = __shfl(idx, e0);
      int s1 = __shfl(idx, e0 + 4);
      int s2 = __shfl(idx, e0 + 8);
      int s3 = __shfl(idx, e0 + 12);
      float4 v0 = *(const float4*)(Y + (size_t)s0 * 64 + q * 4);
      float4 v1 = *(const float4*)(Y + (size_t)s1 * 64 + q * 4);
      float4 v2 = *(const float4*)(Y + (size_t)s2 * 64 + q * 4);
      float4 v3 = *(const float4*)(Y + (size_t)s3 * 64 + q * 4);
      acc.x += (v0.x + v1.x) + (v2.x + v3.x);
      acc.y += (v0.y + v1.y) + (v2.y + v3.y);
      acc.z += (v0.z + v1.z) + (v2.z + v3.z);
      acc.w += (v0.w + v1.w) + (v2.w + v3.w);
    }
    if (eb < m) {  // one masked tail iteration, all lanes active at shfls
      const int e0 = eb + part;
      int s0 = __shfl(idx, e0);
      int s1 = __shfl(idx, e0 + 4);
      int s2 = __shfl(idx, e0 + 8);
      int s3 = __shfl(idx, e0 + 12);
      float4 v0 = *(const float4*)(Y + (size_t)s0 * 64 + q * 4);
      float4 v1 = *(const float4*)(Y + (size_t)s1 * 64 + q * 4);
      float4 v2 = *(const float4*)(Y + (size_t)s2 * 64 + q * 4);
      float4 v3 = *(const float4*)(Y + (size_t)s3 * 64 + q * 4);
      const float m0 = (e0 < m) ? 1.f : 0.f;
      const float m1 = (e0 + 4 < m) ? 1.f : 0.f;
      const float m2 = (e0 + 8 < m) ? 1.f : 0.f;
      const float m3 = (e0 + 12 < m) ? 1.f : 0.f;
      acc.x += (m0 * v0.x + m1 * v1.x) + (m2 * v2.x + m3 * v3.x);
      acc.y += (m0 * v0.y + m1 * v1.y) + (m2 * v2.y + m3 * v3.y);
      acc.z += (m0 * v0.z + m1 * v1.z) + (m2 * v2.z + m3 * v3.z);
      acc.w += (m0 * v0.w + m1 * v1.w) + (m2 * v2.w + m3 * v3.w);
    }
  }

  acc.x += __shfl_xor(acc.x, 16);
  acc.y += __shfl_xor(acc.y, 16);
  acc.z += __shfl_xor(acc.z, 16);
  acc.w += __shfl_xor(acc.w, 16);
  acc.x += __shfl_xor(acc.x, 32);
  acc.y += __shfl_xor(acc.y, 32);
  acc.z += __shfl_xor(acc.z, 32);
  acc.w += __shfl_xor(acc.w, 32);

  if (part == 0) {
    const float dv = dinv[node];
    float4 bb = *(const float4*)(bias + q * 4);
    float4 o;
    o.x = fmaf(acc.x, dv, bb.x);
    o.y = fmaf(acc.y, dv, bb.y);
    o.z = fmaf(acc.z, dv, bb.z);
    o.w = fmaf(acc.w, dv, bb.w);
    *(float4*)(Out + (size_t)node * 64 + q * 4) = o;
  }
}

// ---------------- launch ----------------

extern "C" void kernel_launch(void* const* d_in, const int* in_sizes, int n_in,
                              void* d_out, int out_size, void* d_ws, size_t ws_size,
                              hipStream_t stream) {
  const float* x = (const float*)d_in[0];
  const int* ei = (const int*)d_in[1];
  const float* W1 = (const float*)d_in[2];
  const float* b1 = (const float*)d_in[3];
  const float* W2 = (const float*)d_in[4];
  const float* b2 = (const float*)d_in[5];
  const float* W3 = (const float*)d_in[6];
  const float* b3 = (const float*)d_in[7];
  float* out = (float*)d_out;

  const int* erow = ei;       // edge_index[0] = sources
  const int* ecol = ei + NE;  // edge_index[1] = targets

  char* w = (char*)d_ws;
  auto alloc = [&](size_t b) {
    char* p = w;
    w += (b + 255) & ~(size_t)255;
    return (void*)p;
  };
  int* counts = (int*)alloc((size_t)NN * 4);
  float* dinv = (float*)alloc((size_t)NN * 4);
  int* rowptr = (int*)alloc((size_t)(NN + 1) * 4);
  int* fill = (int*)alloc((size_t)NN * 4);
  int* bsum = (int*)alloc(1024);
  int* srcs = (int*)alloc((size_t)NE * 4);
  float* ybuf = (float*)alloc((size_t)NN * 128 * 4);
  float* hbuf = (float*)alloc((size_t)NN * 128 * 4);

  const int nbN = (NN + 255) / 256;    // 391
  const int nbE = (NE + 255) / 256;    // 6250
  const int nb1 = (NN + 1023) / 1024;  // 98

  k_zero<<<nbN, 256, 0, stream>>>(counts, NN);
  k_hist<<<nbE, 256, 0, stream>>>(ecol, counts, NE);
  k_dinv<<<nbN, 256, 0, stream>>>(counts, dinv, NN);
  k_scan1<<<nb1, 256, 0, stream>>>(counts, rowptr, bsum, NN);
  k_scan2<<<1, 256, 0, stream>>>(bsum, nb1);
  k_scan3<<<nbN, 256, 0, stream>>>(rowptr, bsum, fill, NN, NE);
  k_scatter<<<nbE, 256, 0, stream>>>(erow, ecol, rowptr, fill, srcs, NE);

  const int nbG = (NN + 127) / 128;  // 782
  const int nbA = (NN + 3) / 4;      // 25000

  // Layer 1: x -> hbuf
  k_gemm_scale<128><<<nbG, 256, 0, stream>>>(x, W1, dinv, ybuf, NN);
  k_agg128<true><<<nbA, 256, 0, stream>>>(ybuf, rowptr, srcs, dinv, b1, hbuf, NN);
  // Layer 2: hbuf -> hbuf (via ybuf)
  k_gemm_scale<128><<<nbG, 256, 0, stream>>>(hbuf, W2, dinv, ybuf, NN);
  k_agg128<true><<<nbA, 256, 0, stream>>>(ybuf, rowptr, srcs, dinv, b2, hbuf, NN);
  // Layer 3: hbuf -> out
  k_gemm_scale<64><<<nbG, 256, 0, stream>>>(hbuf, W3, dinv, ybuf, NN);
  k_agg64<<<nbA, 256, 0, stream>>>(ybuf, rowptr, srcs, dinv, b3, out, NN);
}

// Round 4
// 488.280 us; speedup vs baseline: 1.4410x; 1.2609x over previous
//
#include <hip/hip_runtime.h>

#define NN 100000
#define NE 1600000
constexpr int KDIM = 128;
constexpr int NPB = 128;                  // nodes per bucket (col>>7)
constexpr int G = (NN + NPB - 1) / NPB;   // 782 buckets
constexpr int CH = 8192;                  // edges per chunk (bhist/bucket)
constexpr int NCH = (NE + CH - 1) / CH;   // 196 chunks

// ---------------- preprocessing: bucketed counting sort ----------------

__global__ __launch_bounds__(256) void k_zero(int* p, int n) {
  int i = blockIdx.x * 256 + threadIdx.x;
  if (i < n) p[i] = 0;
}

// coarse histogram over G buckets, LDS-staged
__global__ __launch_bounds__(256) void k_bhist(const int* __restrict__ col,
                                               int* __restrict__ bcnt) {
  __shared__ int h[G];
  for (int i = threadIdx.x; i < G; i += 256) h[i] = 0;
  __syncthreads();
  const int base = blockIdx.x * CH;
  const int m = min(CH, NE - base);
  for (int i = threadIdx.x; i < m; i += 256) atomicAdd(&h[col[base + i] >> 7], 1);
  __syncthreads();
  for (int i = threadIdx.x; i < G; i += 256)
    if (h[i]) atomicAdd(&bcnt[i], h[i]);
}

// exclusive scan of G bucket counts -> bbase[0..G], cursor[0..G-1]
__global__ void k_bscan(const int* __restrict__ bcnt, int* __restrict__ bbase,
                        int* __restrict__ cursor) {
  __shared__ int sd[256];
  const int t = threadIdx.x;
  int v[4];
  int s = 0;
#pragma unroll
  for (int j = 0; j < 4; ++j) {
    int idx = t * 4 + j;
    v[j] = (idx < G) ? bcnt[idx] : 0;
    s += v[j];
  }
  sd[t] = s;
  __syncthreads();
  for (int off = 1; off < 256; off <<= 1) {
    int x = (t >= off) ? sd[t - off] : 0;
    __syncthreads();
    sd[t] += x;
    __syncthreads();
  }
  int run = sd[t] - s;  // exclusive prefix
#pragma unroll
  for (int j = 0; j < 4; ++j) {
    int idx = t * 4 + j;
    if (idx < G) {
      bbase[idx] = run;
      cursor[idx] = run;
    }
    run += v[j];
  }
  if (t == 255) bbase[G] = run;  // == NE
}

// bin edges into bucket regions: per-WG LDS hist + bulk reservation + append
__global__ __launch_bounds__(256) void k_bucket(const int* __restrict__ row,
                                                const int* __restrict__ col,
                                                int* __restrict__ cursor,
                                                unsigned long long* __restrict__ temp) {
  __shared__ int h[G];
  for (int i = threadIdx.x; i < G; i += 256) h[i] = 0;
  __syncthreads();
  const int base = blockIdx.x * CH;
  const int m = min(CH, NE - base);
  for (int i = threadIdx.x; i < m; i += 256) atomicAdd(&h[col[base + i] >> 7], 1);
  __syncthreads();
  for (int i = threadIdx.x; i < G; i += 256) {
    int c = h[i];
    if (c) h[i] = atomicAdd(&cursor[i], c);  // h[i] becomes this WG's base slot
  }
  __syncthreads();
  for (int i = threadIdx.x; i < m; i += 256) {
    int cc = col[base + i];
    int rr = row[base + i];
    int slot = atomicAdd(&h[cc >> 7], 1);
    temp[slot] = ((unsigned long long)(unsigned)cc << 32) | (unsigned)rr;
  }
}

// per-bucket: LDS node hist -> scan -> rowptr/dinv, then group srcs
__global__ __launch_bounds__(256) void k_group(const unsigned long long* __restrict__ temp,
                                               const int* __restrict__ bbase,
                                               int* __restrict__ rowptr,
                                               float* __restrict__ dinv,
                                               int* __restrict__ srcs) {
  __shared__ int fill[NPB];
  __shared__ int nbase[NPB];
  __shared__ int sc[NPB];
  const int g = blockIdx.x, t = threadIdx.x;
  const int lo = g * NPB;
  const int b0 = bbase[g], b1 = bbase[g + 1];
  if (t < NPB) fill[t] = 0;
  __syncthreads();
  for (int s = b0 + t; s < b1; s += 256) {
    int cc = (int)(temp[s] >> 32);
    atomicAdd(&fill[cc & (NPB - 1)], 1);
  }
  __syncthreads();
  int v = 0;
  if (t < NPB) {
    v = fill[t];
    sc[t] = v;
  }
  __syncthreads();
  for (int off = 1; off < NPB; off <<= 1) {
    int x = 0;
    if (t < NPB && t >= off) x = sc[t - off];
    __syncthreads();
    if (t < NPB) sc[t] += x;
    __syncthreads();
  }
  if (t < NPB) {
    int excl = sc[t] - v;
    nbase[t] = b0 + excl;
    int node = lo + t;
    if (node < NN) {
      rowptr[node] = b0 + excl;
      dinv[node] = rsqrtf((float)(v + 1));  // +1 self loop
    }
    fill[t] = 0;
  }
  if (g == G - 1 && t == 0) rowptr[NN] = NE;
  __syncthreads();
  for (int s = b0 + t; s < b1; s += 256) {
    unsigned long long p = temp[s];
    int cc = (int)(p >> 32);
    int rr = (int)(unsigned)(p & 0xffffffffull);
    int c = cc & (NPB - 1);
    int slot = atomicAdd(&fill[c], 1);
    srcs[nbase[c] + slot] = rr;
  }
}

// ---------------- GEMM: Y[r,:] = (A[r,:] @ W) * dinv[r] ----------------
// A is [M,128] row-major, W is [128,BN] row-major, Y is [M,BN].
template <int BN>
__global__ __launch_bounds__(256, 2) void k_gemm_scale(const float* __restrict__ A,
                                                       const float* __restrict__ W,
                                                       const float* __restrict__ dinv,
                                                       float* __restrict__ Y, int M) {
  constexpr int BM = 128;
  constexpr int BK = 8;
  constexpr int TX = BN / 8;   // threads along cols (each does 8 cols)
  constexpr int TY = 256 / TX; // threads along rows
  constexpr int MR = BM / TY;  // rows per thread
  constexpr int HR = MR / 2;

  __shared__ float As[BK][BM];
  __shared__ float Bs[BK][BN];

  const int t = threadIdx.x;
  const int rowbase = blockIdx.x * BM;
  const int tx = t % TX;
  const int ty = t / TX;

  float acc[MR][8];
#pragma unroll
  for (int i = 0; i < MR; ++i)
#pragma unroll
    for (int j = 0; j < 8; ++j) acc[i][j] = 0.f;

  const int arow = t >> 1;
  const int akq = (t & 1) * 4;
  const bool avalid = (rowbase + arow) < M;
  const float* aptr = A + (size_t)(rowbase + arow) * KDIM + akq;

  constexpr int BQ = BN / 4;
  const int bk = t / BQ;
  const int bc = (t % BQ) * 4;
  const float* bptr = W + (size_t)(bk < BK ? bk : 0) * BN + bc;

  for (int k0 = 0; k0 < KDIM; k0 += BK) {
    float4 av = make_float4(0.f, 0.f, 0.f, 0.f);
    if (avalid) av = *(const float4*)(aptr + k0);
    float4 bv = make_float4(0.f, 0.f, 0.f, 0.f);
    if (bk < BK) bv = *(const float4*)(bptr + (size_t)k0 * BN);
    __syncthreads();
    As[akq + 0][arow] = av.x;
    As[akq + 1][arow] = av.y;
    As[akq + 2][arow] = av.z;
    As[akq + 3][arow] = av.w;
    if (bk < BK) *(float4*)&Bs[bk][bc] = bv;
    __syncthreads();
#pragma unroll
    for (int k = 0; k < BK; ++k) {
      float a[MR], b[8];
#pragma unroll
      for (int i = 0; i < HR; ++i) {
        a[i] = As[k][ty * HR + i];
        a[HR + i] = As[k][64 + ty * HR + i];
      }
#pragma unroll
      for (int j = 0; j < 4; ++j) {
        b[j] = Bs[k][tx * 4 + j];
        b[4 + j] = Bs[k][BN / 2 + tx * 4 + j];
      }
#pragma unroll
      for (int i = 0; i < MR; ++i)
#pragma unroll
        for (int j = 0; j < 8; ++j) acc[i][j] += a[i] * b[j];
    }
  }

#pragma unroll
  for (int i = 0; i < MR; ++i) {
    int rr = (i < HR) ? (ty * HR + i) : (64 + ty * HR + (i - HR));
    int r = rowbase + rr;
    if (r < M) {
      float dv = dinv[r];
      float* yrow = Y + (size_t)r * BN;
      float4 o0 = make_float4(acc[i][0] * dv, acc[i][1] * dv, acc[i][2] * dv, acc[i][3] * dv);
      float4 o1 = make_float4(acc[i][4] * dv, acc[i][5] * dv, acc[i][6] * dv, acc[i][7] * dv);
      *(float4*)(yrow + tx * 4) = o0;
      *(float4*)(yrow + BN / 2 + tx * 4) = o1;
    }
  }
}

// ---------------- aggregation (latency-optimized, wave-uniform control flow) --
template <bool RELU>
__global__ __launch_bounds__(256) void k_agg128(const float* __restrict__ Y,
                                                const int* __restrict__ rowptr,
                                                const int* __restrict__ srcs,
                                                const float* __restrict__ dinv,
                                                const float* __restrict__ bias,
                                                float* __restrict__ Out, int n) {
  const int wave = threadIdx.x >> 6;
  const int lane = threadIdx.x & 63;
  const int node = blockIdx.x * 4 + wave;
  if (node >= n) return;
  const int half = lane >> 5;  // which edge of the pair
  const int q = lane & 31;     // column quad: cols q*4..q*4+3
  const int jb = rowptr[node];
  const int je = rowptr[node + 1];

  float4 acc = make_float4(0.f, 0.f, 0.f, 0.f);
  if (half == 0) acc = *(const float4*)(Y + (size_t)node * 128 + q * 4);  // self loop

  for (int j0 = jb; j0 < je; j0 += 64) {
    const int m = min(64, je - j0);  // wave-uniform
    int idx = 0;
    if (lane < m) idx = srcs[j0 + lane];
    const int full = m & ~7;  // wave-uniform
    int eb = 0;
    for (; eb < full; eb += 8) {  // uniform trip count: no divergence
      const int e0 = eb + half;
      int s0 = __shfl(idx, e0);
      int s1 = __shfl(idx, e0 + 2);
      int s2 = __shfl(idx, e0 + 4);
      int s3 = __shfl(idx, e0 + 6);
      float4 v0 = *(const float4*)(Y + (size_t)s0 * 128 + q * 4);
      float4 v1 = *(const float4*)(Y + (size_t)s1 * 128 + q * 4);
      float4 v2 = *(const float4*)(Y + (size_t)s2 * 128 + q * 4);
      float4 v3 = *(const float4*)(Y + (size_t)s3 * 128 + q * 4);
      acc.x += (v0.x + v1.x) + (v2.x + v3.x);
      acc.y += (v0.y + v1.y) + (v2.y + v3.y);
      acc.z += (v0.z + v1.z) + (v2.z + v3.z);
      acc.w += (v0.w + v1.w) + (v2.w + v3.w);
    }
    if (eb < m) {  // wave-uniform condition: ONE masked tail iteration
      const int e0 = eb + half;
      int s0 = __shfl(idx, e0);
      int s1 = __shfl(idx, e0 + 2);
      int s2 = __shfl(idx, e0 + 4);
      int s3 = __shfl(idx, e0 + 6);  // sources all active; idx=0 if >= m
      float4 v0 = *(const float4*)(Y + (size_t)s0 * 128 + q * 4);
      float4 v1 = *(const float4*)(Y + (size_t)s1 * 128 + q * 4);
      float4 v2 = *(const float4*)(Y + (size_t)s2 * 128 + q * 4);
      float4 v3 = *(const float4*)(Y + (size_t)s3 * 128 + q * 4);
      const float m0 = (e0 < m) ? 1.f : 0.f;
      const float m1 = (e0 + 2 < m) ? 1.f : 0.f;
      const float m2 = (e0 + 4 < m) ? 1.f : 0.f;
      const float m3 = (e0 + 6 < m) ? 1.f : 0.f;
      acc.x += (m0 * v0.x + m1 * v1.x) + (m2 * v2.x + m3 * v3.x);
      acc.y += (m0 * v0.y + m1 * v1.y) + (m2 * v2.y + m3 * v3.y);
      acc.z += (m0 * v0.z + m1 * v1.z) + (m2 * v2.z + m3 * v3.z);
      acc.w += (m0 * v0.w + m1 * v1.w) + (m2 * v2.w + m3 * v3.w);
    }
  }

  // combine the two half-wave partial sums
  acc.x += __shfl_xor(acc.x, 32);
  acc.y += __shfl_xor(acc.y, 32);
  acc.z += __shfl_xor(acc.z, 32);
  acc.w += __shfl_xor(acc.w, 32);

  if (half == 0) {
    const float dv = dinv[node];
    float4 bb = *(const float4*)(bias + q * 4);
    float4 o;
    o.x = fmaf(acc.x, dv, bb.x);
    o.y = fmaf(acc.y, dv, bb.y);
    o.z = fmaf(acc.z, dv, bb.z);
    o.w = fmaf(acc.w, dv, bb.w);
    if (RELU) {
      o.x = fmaxf(o.x, 0.f);
      o.y = fmaxf(o.y, 0.f);
      o.z = fmaxf(o.z, 0.f);
      o.w = fmaxf(o.w, 0.f);
    }
    *(float4*)(Out + (size_t)node * 128 + q * 4) = o;
  }
}

// D=64: 4 edges per VMEM instr (16 lanes x float4 per row).
__global__ __launch_bounds__(256) void k_agg64(const float* __restrict__ Y,
                                               const int* __restrict__ rowptr,
                                               const int* __restrict__ srcs,
                                               const float* __restrict__ dinv,
                                               const float* __restrict__ bias,
                                               float* __restrict__ Out, int n) {
  const int wave = threadIdx.x >> 6;
  const int lane = threadIdx.x & 63;
  const int node = blockIdx.x * 4 + wave;
  if (node >= n) return;
  const int part = lane >> 4;  // which edge of the quad
  const int q = lane & 15;     // column quad: cols q*4..q*4+3
  const int jb = rowptr[node];
  const int je = rowptr[node + 1];

  float4 acc = make_float4(0.f, 0.f, 0.f, 0.f);
  if (part == 0) acc = *(const float4*)(Y + (size_t)node * 64 + q * 4);  // self loop

  for (int j0 = jb; j0 < je; j0 += 64) {
    const int m = min(64, je - j0);  // wave-uniform
    int idx = 0;
    if (lane < m) idx = srcs[j0 + lane];
    const int full = m & ~15;  // wave-uniform
    int eb = 0;
    for (; eb < full; eb += 16) {
      const int e0 = eb + part;
      int s0 = __shfl(idx, e0);
      int s1 = __shfl(idx, e0 + 4);
      int s2 = __shfl(idx, e0 + 8);
      int s3 = __shfl(idx, e0 + 12);
      float4 v0 = *(const float4*)(Y + (size_t)s0 * 64 + q * 4);
      float4 v1 = *(const float4*)(Y + (size_t)s1 * 64 + q * 4);
      float4 v2 = *(const float4*)(Y + (size_t)s2 * 64 + q * 4);
      float4 v3 = *(const float4*)(Y + (size_t)s3 * 64 + q * 4);
      acc.x += (v0.x + v1.x) + (v2.x + v3.x);
      acc.y += (v0.y + v1.y) + (v2.y + v3.y);
      acc.z += (v0.z + v1.z) + (v2.z + v3.z);
      acc.w += (v0.w + v1.w) + (v2.w + v3.w);
    }
    if (eb < m) {  // one masked tail iteration, all lanes active at shfls
      const int e0 = eb + part;
      int s0 = __shfl(idx, e0);
      int s1 = __shfl(idx, e0 + 4);
      int s2 = __shfl(idx, e0 + 8);
      int s3 = __shfl(idx, e0 + 12);
      float4 v0 = *(const float4*)(Y + (size_t)s0 * 64 + q * 4);
      float4 v1 = *(const float4*)(Y + (size_t)s1 * 64 + q * 4);
      float4 v2 = *(const float4*)(Y + (size_t)s2 * 64 + q * 4);
      float4 v3 = *(const float4*)(Y + (size_t)s3 * 64 + q * 4);
      const float m0 = (e0 < m) ? 1.f : 0.f;
      const float m1 = (e0 + 4 < m) ? 1.f : 0.f;
      const float m2 = (e0 + 8 < m) ? 1.f : 0.f;
      const float m3 = (e0 + 12 < m) ? 1.f : 0.f;
      acc.x += (m0 * v0.x + m1 * v1.x) + (m2 * v2.x + m3 * v3.x);
      acc.y += (m0 * v0.y + m1 * v1.y) + (m2 * v2.y + m3 * v3.y);
      acc.z += (m0 * v0.z + m1 * v1.z) + (m2 * v2.z + m3 * v3.z);
      acc.w += (m0 * v0.w + m1 * v1.w) + (m2 * v2.w + m3 * v3.w);
    }
  }

  acc.x += __shfl_xor(acc.x, 16);
  acc.y += __shfl_xor(acc.y, 16);
  acc.z += __shfl_xor(acc.z, 16);
  acc.w += __shfl_xor(acc.w, 16);
  acc.x += __shfl_xor(acc.x, 32);
  acc.y += __shfl_xor(acc.y, 32);
  acc.z += __shfl_xor(acc.z, 32);
  acc.w += __shfl_xor(acc.w, 32);

  if (part == 0) {
    const float dv = dinv[node];
    float4 bb = *(const float4*)(bias + q * 4);
    float4 o;
    o.x = fmaf(acc.x, dv, bb.x);
    o.y = fmaf(acc.y, dv, bb.y);
    o.z = fmaf(acc.z, dv, bb.z);
    o.w = fmaf(acc.w, dv, bb.w);
    *(float4*)(Out + (size_t)node * 64 + q * 4) = o;
  }
}

// ---------------- launch ----------------

extern "C" void kernel_launch(void* const* d_in, const int* in_sizes, int n_in,
                              void* d_out, int out_size, void* d_ws, size_t ws_size,
                              hipStream_t stream) {
  const float* x = (const float*)d_in[0];
  const int* ei = (const int*)d_in[1];
  const float* W1 = (const float*)d_in[2];
  const float* b1 = (const float*)d_in[3];
  const float* W2 = (const float*)d_in[4];
  const float* b2 = (const float*)d_in[5];
  const float* W3 = (const float*)d_in[6];
  const float* b3 = (const float*)d_in[7];
  float* out = (float*)d_out;

  const int* erow = ei;       // edge_index[0] = sources
  const int* ecol = ei + NE;  // edge_index[1] = targets

  char* w = (char*)d_ws;
  auto alloc = [&](size_t b) {
    char* p = w;
    w += (b + 255) & ~(size_t)255;
    return (void*)p;
  };
  float* dinv = (float*)alloc((size_t)NN * 4);
  int* rowptr = (int*)alloc((size_t)(NN + 1) * 4);
  int* bcnt = (int*)alloc((size_t)(G + 1) * 4);
  int* bbase = (int*)alloc((size_t)(G + 1) * 4);
  int* cursor = (int*)alloc((size_t)G * 4);
  int* srcs = (int*)alloc((size_t)NE * 4);
  float* ybuf = (float*)alloc((size_t)NN * 128 * 4);
  float* hbuf = (float*)alloc((size_t)NN * 128 * 4);
  // temp edge pairs alias ybuf (dead until first GEMM writes it)
  unsigned long long* temp = (unsigned long long*)ybuf;

  // preprocessing: bucketed counting sort -> rowptr, srcs, dinv
  k_zero<<<(G + 255) / 256, 256, 0, stream>>>(bcnt, G);
  k_bhist<<<NCH, 256, 0, stream>>>(ecol, bcnt);
  k_bscan<<<1, 256, 0, stream>>>(bcnt, bbase, cursor);
  k_bucket<<<NCH, 256, 0, stream>>>(erow, ecol, cursor, temp);
  k_group<<<G, 256, 0, stream>>>(temp, bbase, rowptr, dinv, srcs);

  const int nbG = (NN + 127) / 128;  // 782
  const int nbA = (NN + 3) / 4;      // 25000

  // Layer 1: x -> hbuf
  k_gemm_scale<128><<<nbG, 256, 0, stream>>>(x, W1, dinv, ybuf, NN);
  k_agg128<true><<<nbA, 256, 0, stream>>>(ybuf, rowptr, srcs, dinv, b1, hbuf, NN);
  // Layer 2: hbuf -> hbuf (via ybuf)
  k_gemm_scale<128><<<nbG, 256, 0, stream>>>(hbuf, W2, dinv, ybuf, NN);
  k_agg128<true><<<nbA, 256, 0, stream>>>(ybuf, rowptr, srcs, dinv, b2, hbuf, NN);
  // Layer 3: hbuf -> out
  k_gemm_scale<64><<<nbG, 256, 0, stream>>>(hbuf, W3, dinv, ybuf, NN);
  k_agg64<<<nbA, 256, 0, stream>>>(ybuf, rowptr, srcs, dinv, b3, out, NN);
}

// Round 5
// 352.362 us; speedup vs baseline: 1.9969x; 1.3857x over previous
//
#include <hip/hip_runtime.h>

#define NN 100000
#define NE 1600000
constexpr int KDIM = 128;
constexpr int NPB = 128;                  // nodes per bucket (col>>7)
constexpr int G = (NN + NPB - 1) / NPB;   // 782 buckets
constexpr int CH = 8192;                  // edges per chunk (bhist/bucket)
constexpr int NCH = (NE + CH - 1) / CH;   // 196 chunks

using half4 = _Float16 __attribute__((ext_vector_type(4)));
using half8 = _Float16 __attribute__((ext_vector_type(8)));

// ---------------- preprocessing: bucketed counting sort ----------------

__global__ __launch_bounds__(256) void k_zero(int* p, int n) {
  int i = blockIdx.x * 256 + threadIdx.x;
  if (i < n) p[i] = 0;
}

// coarse histogram over G buckets, LDS-staged
__global__ __launch_bounds__(256) void k_bhist(const int* __restrict__ col,
                                               int* __restrict__ bcnt) {
  __shared__ int h[G];
  for (int i = threadIdx.x; i < G; i += 256) h[i] = 0;
  __syncthreads();
  const int base = blockIdx.x * CH;
  const int m = min(CH, NE - base);
  for (int i = threadIdx.x; i < m; i += 256) atomicAdd(&h[col[base + i] >> 7], 1);
  __syncthreads();
  for (int i = threadIdx.x; i < G; i += 256)
    if (h[i]) atomicAdd(&bcnt[i], h[i]);
}

// exclusive scan of G bucket counts -> bbase[0..G], cursor[0..G-1]
__global__ void k_bscan(const int* __restrict__ bcnt, int* __restrict__ bbase,
                        int* __restrict__ cursor) {
  __shared__ int sd[256];
  const int t = threadIdx.x;
  int v[4];
  int s = 0;
#pragma unroll
  for (int j = 0; j < 4; ++j) {
    int idx = t * 4 + j;
    v[j] = (idx < G) ? bcnt[idx] : 0;
    s += v[j];
  }
  sd[t] = s;
  __syncthreads();
  for (int off = 1; off < 256; off <<= 1) {
    int x = (t >= off) ? sd[t - off] : 0;
    __syncthreads();
    sd[t] += x;
    __syncthreads();
  }
  int run = sd[t] - s;  // exclusive prefix
#pragma unroll
  for (int j = 0; j < 4; ++j) {
    int idx = t * 4 + j;
    if (idx < G) {
      bbase[idx] = run;
      cursor[idx] = run;
    }
    run += v[j];
  }
  if (t == 255) bbase[G] = run;  // == NE
}

// bin edges into bucket regions: per-WG LDS hist + bulk reservation + append
__global__ __launch_bounds__(256) void k_bucket(const int* __restrict__ row,
                                                const int* __restrict__ col,
                                                int* __restrict__ cursor,
                                                unsigned long long* __restrict__ temp) {
  __shared__ int h[G];
  for (int i = threadIdx.x; i < G; i += 256) h[i] = 0;
  __syncthreads();
  const int base = blockIdx.x * CH;
  const int m = min(CH, NE - base);
  for (int i = threadIdx.x; i < m; i += 256) atomicAdd(&h[col[base + i] >> 7], 1);
  __syncthreads();
  for (int i = threadIdx.x; i < G; i += 256) {
    int c = h[i];
    if (c) h[i] = atomicAdd(&cursor[i], c);  // h[i] becomes this WG's base slot
  }
  __syncthreads();
  for (int i = threadIdx.x; i < m; i += 256) {
    int cc = col[base + i];
    int rr = row[base + i];
    int slot = atomicAdd(&h[cc >> 7], 1);
    temp[slot] = ((unsigned long long)(unsigned)cc << 32) | (unsigned)rr;
  }
}

// per-bucket: LDS node hist -> scan -> rowptr/dinv, then group srcs
__global__ __launch_bounds__(256) void k_group(const unsigned long long* __restrict__ temp,
                                               const int* __restrict__ bbase,
                                               int* __restrict__ rowptr,
                                               float* __restrict__ dinv,
                                               int* __restrict__ srcs) {
  __shared__ int fill[NPB];
  __shared__ int nbase[NPB];
  __shared__ int sc[NPB];
  const int g = blockIdx.x, t = threadIdx.x;
  const int lo = g * NPB;
  const int b0 = bbase[g], b1 = bbase[g + 1];
  if (t < NPB) fill[t] = 0;
  __syncthreads();
  for (int s = b0 + t; s < b1; s += 256) {
    int cc = (int)(temp[s] >> 32);
    atomicAdd(&fill[cc & (NPB - 1)], 1);
  }
  __syncthreads();
  int v = 0;
  if (t < NPB) {
    v = fill[t];
    sc[t] = v;
  }
  __syncthreads();
  for (int off = 1; off < NPB; off <<= 1) {
    int x = 0;
    if (t < NPB && t >= off) x = sc[t - off];
    __syncthreads();
    if (t < NPB) sc[t] += x;
    __syncthreads();
  }
  if (t < NPB) {
    int excl = sc[t] - v;
    nbase[t] = b0 + excl;
    int node = lo + t;
    if (node < NN) {
      rowptr[node] = b0 + excl;
      dinv[node] = rsqrtf((float)(v + 1));  // +1 self loop
    }
    fill[t] = 0;
  }
  if (g == G - 1 && t == 0) rowptr[NN] = NE;
  __syncthreads();
  for (int s = b0 + t; s < b1; s += 256) {
    unsigned long long p = temp[s];
    int cc = (int)(p >> 32);
    int rr = (int)(unsigned)(p & 0xffffffffull);
    int c = cc & (NPB - 1);
    int slot = atomicAdd(&fill[c], 1);
    srcs[nbase[c] + slot] = rr;
  }
}

// ---------------- GEMM: Y[r,:] = fp16((A[r,:] @ W) * dinv[r]) ----------------
// A is [M,128] row-major fp32, W is [128,BN] row-major fp32, Y is [M,BN] fp16.
template <int BN>
__global__ __launch_bounds__(256, 2) void k_gemm_scale(const float* __restrict__ A,
                                                       const float* __restrict__ W,
                                                       const float* __restrict__ dinv,
                                                       _Float16* __restrict__ Y, int M) {
  constexpr int BM = 128;
  constexpr int BK = 8;
  constexpr int TX = BN / 8;   // threads along cols (each does 8 cols)
  constexpr int TY = 256 / TX; // threads along rows
  constexpr int MR = BM / TY;  // rows per thread
  constexpr int HR = MR / 2;

  __shared__ float As[BK][BM];
  __shared__ float Bs[BK][BN];

  const int t = threadIdx.x;
  const int rowbase = blockIdx.x * BM;
  const int tx = t % TX;
  const int ty = t / TX;

  float acc[MR][8];
#pragma unroll
  for (int i = 0; i < MR; ++i)
#pragma unroll
    for (int j = 0; j < 8; ++j) acc[i][j] = 0.f;

  const int arow = t >> 1;
  const int akq = (t & 1) * 4;
  const bool avalid = (rowbase + arow) < M;
  const float* aptr = A + (size_t)(rowbase + arow) * KDIM + akq;

  constexpr int BQ = BN / 4;
  const int bk = t / BQ;
  const int bc = (t % BQ) * 4;
  const float* bptr = W + (size_t)(bk < BK ? bk : 0) * BN + bc;

  for (int k0 = 0; k0 < KDIM; k0 += BK) {
    float4 av = make_float4(0.f, 0.f, 0.f, 0.f);
    if (avalid) av = *(const float4*)(aptr + k0);
    float4 bv = make_float4(0.f, 0.f, 0.f, 0.f);
    if (bk < BK) bv = *(const float4*)(bptr + (size_t)k0 * BN);
    __syncthreads();
    As[akq + 0][arow] = av.x;
    As[akq + 1][arow] = av.y;
    As[akq + 2][arow] = av.z;
    As[akq + 3][arow] = av.w;
    if (bk < BK) *(float4*)&Bs[bk][bc] = bv;
    __syncthreads();
#pragma unroll
    for (int k = 0; k < BK; ++k) {
      float a[MR], b[8];
#pragma unroll
      for (int i = 0; i < HR; ++i) {
        a[i] = As[k][ty * HR + i];
        a[HR + i] = As[k][64 + ty * HR + i];
      }
#pragma unroll
      for (int j = 0; j < 4; ++j) {
        b[j] = Bs[k][tx * 4 + j];
        b[4 + j] = Bs[k][BN / 2 + tx * 4 + j];
      }
#pragma unroll
      for (int i = 0; i < MR; ++i)
#pragma unroll
        for (int j = 0; j < 8; ++j) acc[i][j] += a[i] * b[j];
    }
  }

#pragma unroll
  for (int i = 0; i < MR; ++i) {
    int rr = (i < HR) ? (ty * HR + i) : (64 + ty * HR + (i - HR));
    int r = rowbase + rr;
    if (r < M) {
      float dv = dinv[r];
      _Float16* yrow = Y + (size_t)r * BN;
      half4 h0 = {(_Float16)(acc[i][0] * dv), (_Float16)(acc[i][1] * dv),
                  (_Float16)(acc[i][2] * dv), (_Float16)(acc[i][3] * dv)};
      half4 h1 = {(_Float16)(acc[i][4] * dv), (_Float16)(acc[i][5] * dv),
                  (_Float16)(acc[i][6] * dv), (_Float16)(acc[i][7] * dv)};
      *(half4*)(yrow + tx * 4) = h0;
      *(half4*)(yrow + BN / 2 + tx * 4) = h1;
    }
  }
}

// ---------------- aggregation (fp16 y, wave-uniform control flow) ------------
// Row = 128 fp16 = 256 B = 16 lanes x 16 B -> 4 edges per VMEM instr.
// All trip counts wave-uniform; masked single tail iteration (round-3 lesson).
template <bool RELU>
__global__ __launch_bounds__(256) void k_agg128h(const _Float16* __restrict__ Y,
                                                 const int* __restrict__ rowptr,
                                                 const int* __restrict__ srcs,
                                                 const float* __restrict__ dinv,
                                                 const float* __restrict__ bias,
                                                 float* __restrict__ Out, int n) {
  const int wave = threadIdx.x >> 6;
  const int lane = threadIdx.x & 63;
  const int node = blockIdx.x * 4 + wave;
  if (node >= n) return;
  const int part = lane >> 4;  // which edge of the quad (0..3)
  const int q = lane & 15;     // element block: cols q*8..q*8+7
  const int jb = rowptr[node];
  const int je = rowptr[node + 1];

  float acc[8];
#pragma unroll
  for (int j = 0; j < 8; ++j) acc[j] = 0.f;
  if (part == 0) {  // self loop
    half8 s = *(const half8*)(Y + (size_t)node * 128 + q * 8);
#pragma unroll
    for (int j = 0; j < 8; ++j) acc[j] = (float)s[j];
  }

  for (int j0 = jb; j0 < je; j0 += 64) {
    const int m = min(64, je - j0);  // wave-uniform
    int idx = 0;
    if (lane < m) idx = srcs[j0 + lane];
    const int full = m & ~15;  // wave-uniform
    int eb = 0;
    for (; eb < full; eb += 16) {  // uniform trip count
      const int e0 = eb + part;
      int s0 = __shfl(idx, e0);
      int s1 = __shfl(idx, e0 + 4);
      int s2 = __shfl(idx, e0 + 8);
      int s3 = __shfl(idx, e0 + 12);
      half8 v0 = *(const half8*)(Y + (size_t)s0 * 128 + q * 8);
      half8 v1 = *(const half8*)(Y + (size_t)s1 * 128 + q * 8);
      half8 v2 = *(const half8*)(Y + (size_t)s2 * 128 + q * 8);
      half8 v3 = *(const half8*)(Y + (size_t)s3 * 128 + q * 8);
#pragma unroll
      for (int j = 0; j < 8; ++j)
        acc[j] += ((float)v0[j] + (float)v1[j]) + ((float)v2[j] + (float)v3[j]);
    }
    if (eb < m) {  // ONE masked tail iteration, all lanes active at shfls
      const int e0 = eb + part;
      int s0 = __shfl(idx, e0);
      int s1 = __shfl(idx, e0 + 4);
      int s2 = __shfl(idx, e0 + 8);
      int s3 = __shfl(idx, e0 + 12);
      half8 v0 = *(const half8*)(Y + (size_t)s0 * 128 + q * 8);
      half8 v1 = *(const half8*)(Y + (size_t)s1 * 128 + q * 8);
      half8 v2 = *(const half8*)(Y + (size_t)s2 * 128 + q * 8);
      half8 v3 = *(const half8*)(Y + (size_t)s3 * 128 + q * 8);
      const float m0 = (e0 < m) ? 1.f : 0.f;
      const float m1 = (e0 + 4 < m) ? 1.f : 0.f;
      const float m2 = (e0 + 8 < m) ? 1.f : 0.f;
      const float m3 = (e0 + 12 < m) ? 1.f : 0.f;
#pragma unroll
      for (int j = 0; j < 8; ++j)
        acc[j] += (m0 * (float)v0[j] + m1 * (float)v1[j]) +
                  (m2 * (float)v2[j] + m3 * (float)v3[j]);
    }
  }

  // combine the four part partial sums
#pragma unroll
  for (int j = 0; j < 8; ++j) {
    acc[j] += __shfl_xor(acc[j], 16);
    acc[j] += __shfl_xor(acc[j], 32);
  }

  if (part == 0) {
    const float dv = dinv[node];
    float o[8];
#pragma unroll
    for (int j = 0; j < 8; ++j) {
      o[j] = fmaf(acc[j], dv, bias[q * 8 + j]);
      if (RELU) o[j] = fmaxf(o[j], 0.f);
    }
    float* orow = Out + (size_t)node * 128 + q * 8;
    *(float4*)(orow) = make_float4(o[0], o[1], o[2], o[3]);
    *(float4*)(orow + 4) = make_float4(o[4], o[5], o[6], o[7]);
  }
}

// D=64: row = 64 fp16 = 128 B = 8 lanes x 16 B -> 8 edges per VMEM instr.
__global__ __launch_bounds__(256) void k_agg64h(const _Float16* __restrict__ Y,
                                                const int* __restrict__ rowptr,
                                                const int* __restrict__ srcs,
                                                const float* __restrict__ dinv,
                                                const float* __restrict__ bias,
                                                float* __restrict__ Out, int n) {
  const int wave = threadIdx.x >> 6;
  const int lane = threadIdx.x & 63;
  const int node = blockIdx.x * 4 + wave;
  if (node >= n) return;
  const int part = lane >> 3;  // which edge of the octet (0..7)
  const int q = lane & 7;      // element block: cols q*8..q*8+7
  const int jb = rowptr[node];
  const int je = rowptr[node + 1];

  float acc[8];
#pragma unroll
  for (int j = 0; j < 8; ++j) acc[j] = 0.f;
  if (part == 0) {  // self loop
    half8 s = *(const half8*)(Y + (size_t)node * 64 + q * 8);
#pragma unroll
    for (int j = 0; j < 8; ++j) acc[j] = (float)s[j];
  }

  for (int j0 = jb; j0 < je; j0 += 64) {
    const int m = min(64, je - j0);  // wave-uniform
    int idx = 0;
    if (lane < m) idx = srcs[j0 + lane];
    const int full = m & ~31;  // wave-uniform
    int eb = 0;
    for (; eb < full; eb += 32) {
      const int e0 = eb + part;
      int s0 = __shfl(idx, e0);
      int s1 = __shfl(idx, e0 + 8);
      int s2 = __shfl(idx, e0 + 16);
      int s3 = __shfl(idx, e0 + 24);
      half8 v0 = *(const half8*)(Y + (size_t)s0 * 64 + q * 8);
      half8 v1 = *(const half8*)(Y + (size_t)s1 * 64 + q * 8);
      half8 v2 = *(const half8*)(Y + (size_t)s2 * 64 + q * 8);
      half8 v3 = *(const half8*)(Y + (size_t)s3 * 64 + q * 8);
#pragma unroll
      for (int j = 0; j < 8; ++j)
        acc[j] += ((float)v0[j] + (float)v1[j]) + ((float)v2[j] + (float)v3[j]);
    }
    if (eb < m) {  // one masked tail iteration
      const int e0 = eb + part;
      int s0 = __shfl(idx, e0);
      int s1 = __shfl(idx, e0 + 8);
      int s2 = __shfl(idx, e0 + 16);
      int s3 = __shfl(idx, e0 + 24);
      half8 v0 = *(const half8*)(Y + (size_t)s0 * 64 + q * 8);
      half8 v1 = *(const half8*)(Y + (size_t)s1 * 64 + q * 8);
      half8 v2 = *(const half8*)(Y + (size_t)s2 * 64 + q * 8);
      half8 v3 = *(const half8*)(Y + (size_t)s3 * 64 + q * 8);
      const float m0 = (e0 < m) ? 1.f : 0.f;
      const float m1 = (e0 + 8 < m) ? 1.f : 0.f;
      const float m2 = (e0 + 16 < m) ? 1.f : 0.f;
      const float m3 = (e0 + 24 < m) ? 1.f : 0.f;
#pragma unroll
      for (int j = 0; j < 8; ++j)
        acc[j] += (m0 * (float)v0[j] + m1 * (float)v1[j]) +
                  (m2 * (float)v2[j] + m3 * (float)v3[j]);
    }
  }

#pragma unroll
  for (int j = 0; j < 8; ++j) {
    acc[j] += __shfl_xor(acc[j], 8);
    acc[j] += __shfl_xor(acc[j], 16);
    acc[j] += __shfl_xor(acc[j], 32);
  }

  if (part == 0) {
    const float dv = dinv[node];
    float o[8];
#pragma unroll
    for (int j = 0; j < 8; ++j) o[j] = fmaf(acc[j], dv, bias[q * 8 + j]);
    float* orow = Out + (size_t)node * 64 + q * 8;
    *(float4*)(orow) = make_float4(o[0], o[1], o[2], o[3]);
    *(float4*)(orow + 4) = make_float4(o[4], o[5], o[6], o[7]);
  }
}

// ---------------- launch ----------------

extern "C" void kernel_launch(void* const* d_in, const int* in_sizes, int n_in,
                              void* d_out, int out_size, void* d_ws, size_t ws_size,
                              hipStream_t stream) {
  const float* x = (const float*)d_in[0];
  const int* ei = (const int*)d_in[1];
  const float* W1 = (const float*)d_in[2];
  const float* b1 = (const float*)d_in[3];
  const float* W2 = (const float*)d_in[4];
  const float* b2 = (const float*)d_in[5];
  const float* W3 = (const float*)d_in[6];
  const float* b3 = (const float*)d_in[7];
  float* out = (float*)d_out;

  const int* erow = ei;       // edge_index[0] = sources
  const int* ecol = ei + NE;  // edge_index[1] = targets

  char* w = (char*)d_ws;
  auto alloc = [&](size_t b) {
    char* p = w;
    w += (b + 255) & ~(size_t)255;
    return (void*)p;
  };
  float* dinv = (float*)alloc((size_t)NN * 4);
  int* rowptr = (int*)alloc((size_t)(NN + 1) * 4);
  int* bcnt = (int*)alloc((size_t)(G + 1) * 4);
  int* bbase = (int*)alloc((size_t)(G + 1) * 4);
  int* cursor = (int*)alloc((size_t)G * 4);
  int* srcs = (int*)alloc((size_t)NE * 4);
  _Float16* ybuf = (_Float16*)alloc((size_t)NN * 128 * 2);  // fp16 y
  float* hbuf = (float*)alloc((size_t)NN * 128 * 4);
  // temp edge pairs (12.8 MB) alias ybuf (25.6 MB, dead until first GEMM)
  unsigned long long* temp = (unsigned long long*)ybuf;

  // preprocessing: bucketed counting sort -> rowptr, srcs, dinv
  k_zero<<<(G + 255) / 256, 256, 0, stream>>>(bcnt, G);
  k_bhist<<<NCH, 256, 0, stream>>>(ecol, bcnt);
  k_bscan<<<1, 256, 0, stream>>>(bcnt, bbase, cursor);
  k_bucket<<<NCH, 256, 0, stream>>>(erow, ecol, cursor, temp);
  k_group<<<G, 256, 0, stream>>>(temp, bbase, rowptr, dinv, srcs);

  const int nbG = (NN + 127) / 128;  // 782
  const int nbA = (NN + 3) / 4;      // 25000

  // Layer 1: x -> hbuf
  k_gemm_scale<128><<<nbG, 256, 0, stream>>>(x, W1, dinv, ybuf, NN);
  k_agg128h<true><<<nbA, 256, 0, stream>>>(ybuf, rowptr, srcs, dinv, b1, hbuf, NN);
  // Layer 2: hbuf -> hbuf (via ybuf)
  k_gemm_scale<128><<<nbG, 256, 0, stream>>>(hbuf, W2, dinv, ybuf, NN);
  k_agg128h<true><<<nbA, 256, 0, stream>>>(ybuf, rowptr, srcs, dinv, b2, hbuf, NN);
  // Layer 3: hbuf -> out
  k_gemm_scale<64><<<nbG, 256, 0, stream>>>(hbuf, W3, dinv, ybuf, NN);
  k_agg64h<<<nbA, 256, 0, stream>>>(ybuf, rowptr, srcs, dinv, b3, out, NN);
}

// Round 6
// 284.640 us; speedup vs baseline: 2.4720x; 1.2379x over previous
//
#include <hip/hip_runtime.h>

#define NN 100000
#define NE 1600000
constexpr int KDIM = 128;
constexpr int NPB = 128;                  // nodes per bucket (col>>7)
constexpr int G = (NN + NPB - 1) / NPB;   // 782 buckets
constexpr int CH = 8192;                  // edges per chunk (bhist/bucket)
constexpr int NCH = (NE + CH - 1) / CH;   // 196 chunks

typedef _Float16 f16x4 __attribute__((ext_vector_type(4)));
typedef _Float16 f16x8 __attribute__((ext_vector_type(8)));
typedef float f32x4 __attribute__((ext_vector_type(4)));
using half8 = f16x8;

// LDS XOR swizzle for 256B-row-stride b128 access (G4): uniform bank slots
__device__ __forceinline__ int swz(int byte) {
  return byte ^ (((byte >> 8) & 7) << 4);
}

// ---------------- preprocessing: bucketed counting sort ----------------

__global__ __launch_bounds__(256) void k_zero(int* p, int n) {
  int i = blockIdx.x * 256 + threadIdx.x;
  if (i < n) p[i] = 0;
}

__global__ __launch_bounds__(256) void k_bhist(const int* __restrict__ col,
                                               int* __restrict__ bcnt) {
  __shared__ int h[G];
  for (int i = threadIdx.x; i < G; i += 256) h[i] = 0;
  __syncthreads();
  const int base = blockIdx.x * CH;
  const int m = min(CH, NE - base);
  for (int i = threadIdx.x; i < m; i += 256) atomicAdd(&h[col[base + i] >> 7], 1);
  __syncthreads();
  for (int i = threadIdx.x; i < G; i += 256)
    if (h[i]) atomicAdd(&bcnt[i], h[i]);
}

__global__ void k_bscan(const int* __restrict__ bcnt, int* __restrict__ bbase,
                        int* __restrict__ cursor) {
  __shared__ int sd[256];
  const int t = threadIdx.x;
  int v[4];
  int s = 0;
#pragma unroll
  for (int j = 0; j < 4; ++j) {
    int idx = t * 4 + j;
    v[j] = (idx < G) ? bcnt[idx] : 0;
    s += v[j];
  }
  sd[t] = s;
  __syncthreads();
  for (int off = 1; off < 256; off <<= 1) {
    int x = (t >= off) ? sd[t - off] : 0;
    __syncthreads();
    sd[t] += x;
    __syncthreads();
  }
  int run = sd[t] - s;  // exclusive prefix
#pragma unroll
  for (int j = 0; j < 4; ++j) {
    int idx = t * 4 + j;
    if (idx < G) {
      bbase[idx] = run;
      cursor[idx] = run;
    }
    run += v[j];
  }
  if (t == 255) bbase[G] = run;  // == NE
}

__global__ __launch_bounds__(256) void k_bucket(const int* __restrict__ row,
                                                const int* __restrict__ col,
                                                int* __restrict__ cursor,
                                                unsigned long long* __restrict__ temp) {
  __shared__ int h[G];
  for (int i = threadIdx.x; i < G; i += 256) h[i] = 0;
  __syncthreads();
  const int base = blockIdx.x * CH;
  const int m = min(CH, NE - base);
  for (int i = threadIdx.x; i < m; i += 256) atomicAdd(&h[col[base + i] >> 7], 1);
  __syncthreads();
  for (int i = threadIdx.x; i < G; i += 256) {
    int c = h[i];
    if (c) h[i] = atomicAdd(&cursor[i], c);  // h[i] becomes this WG's base slot
  }
  __syncthreads();
  for (int i = threadIdx.x; i < m; i += 256) {
    int cc = col[base + i];
    int rr = row[base + i];
    int slot = atomicAdd(&h[cc >> 7], 1);
    temp[slot] = ((unsigned long long)(unsigned)cc << 32) | (unsigned)rr;
  }
}

__global__ __launch_bounds__(256) void k_group(const unsigned long long* __restrict__ temp,
                                               const int* __restrict__ bbase,
                                               int* __restrict__ rowptr,
                                               float* __restrict__ dinv,
                                               int* __restrict__ srcs) {
  __shared__ int fill[NPB];
  __shared__ int nbase[NPB];
  __shared__ int sc[NPB];
  const int g = blockIdx.x, t = threadIdx.x;
  const int lo = g * NPB;
  const int b0 = bbase[g], b1 = bbase[g + 1];
  if (t < NPB) fill[t] = 0;
  __syncthreads();
  for (int s = b0 + t; s < b1; s += 256) {
    int cc = (int)(temp[s] >> 32);
    atomicAdd(&fill[cc & (NPB - 1)], 1);
  }
  __syncthreads();
  int v = 0;
  if (t < NPB) {
    v = fill[t];
    sc[t] = v;
  }
  __syncthreads();
  for (int off = 1; off < NPB; off <<= 1) {
    int x = 0;
    if (t < NPB && t >= off) x = sc[t - off];
    __syncthreads();
    if (t < NPB) sc[t] += x;
    __syncthreads();
  }
  if (t < NPB) {
    int excl = sc[t] - v;
    nbase[t] = b0 + excl;
    int node = lo + t;
    if (node < NN) {
      rowptr[node] = b0 + excl;
      dinv[node] = rsqrtf((float)(v + 1));  // +1 self loop
    }
    fill[t] = 0;
  }
  if (g == G - 1 && t == 0) rowptr[NN] = NE;
  __syncthreads();
  for (int s = b0 + t; s < b1; s += 256) {
    unsigned long long p = temp[s];
    int cc = (int)(p >> 32);
    int rr = (int)(unsigned)(p & 0xffffffffull);
    int c = cc & (NPB - 1);
    int slot = atomicAdd(&fill[c], 1);
    srcs[nbase[c] + slot] = rr;
  }
}

// -------- weight convert: W fp32 [128][N] -> Wt fp16 [N][128] (transposed) ---
__global__ __launch_bounds__(256) void k_wconv(const float* __restrict__ W,
                                               _Float16* __restrict__ Wt, int N) {
  int i = blockIdx.x * 256 + threadIdx.x;
  if (i < 128 * N) {
    int k = i / N, c = i % N;
    Wt[c * 128 + k] = (_Float16)W[i];
  }
}

// ---------------- MFMA GEMM: Y = A @ W, fp16 in/out, fp32 accumulate --------
// A: [M,128] (fp32 with dinv row-prescale if F32IN, else fp16 pre-scaled).
// Wt_g: fp16 [BN][128] (transposed weights). Y: fp16 [M,BN].
// Swapped-operand mfma(Wfrag, Afrag) -> lane holds 4 consecutive output cols.
template <int BN, bool F32IN>
__global__ __launch_bounds__(256, 2) void k_gemm_mfma(const void* __restrict__ Ain,
                                                      const _Float16* __restrict__ Wt_g,
                                                      const float* __restrict__ dinv,
                                                      _Float16* __restrict__ Y, int M) {
  constexpr int NB = BN / 16;
  __shared__ _Float16 Ah[128 * 128];  // 32 KB, swizzled rows of 256 B
  __shared__ _Float16 Wt[BN * 128];   // 32/16 KB, swizzled
  const int t = threadIdx.x;
  const int rbase = blockIdx.x * 128;

  // stage Wt (coalesced half8 copy, swizzled LDS write)
  for (int c = t; c < BN * 16; c += 256) {
    f16x8 v = *(const f16x8*)((const char*)Wt_g + c * 16);
    *(f16x8*)((char*)Wt + swz(c * 16)) = v;
  }
  // stage A (128 rows x 16 chunks of 8 halves)
  if constexpr (F32IN) {
    const float* A = (const float*)Ain;
    for (int c = t; c < 2048; c += 256) {
      int r = c >> 4, kc = c & 15;
      int row = rbase + r;
      f16x8 h = {};
      if (row < M) {
        float dv = dinv[row];
        const float* p = A + (size_t)row * 128 + kc * 8;
        float4 u0 = *(const float4*)p;
        float4 u1 = *(const float4*)(p + 4);
        h[0] = (_Float16)(u0.x * dv);
        h[1] = (_Float16)(u0.y * dv);
        h[2] = (_Float16)(u0.z * dv);
        h[3] = (_Float16)(u0.w * dv);
        h[4] = (_Float16)(u1.x * dv);
        h[5] = (_Float16)(u1.y * dv);
        h[6] = (_Float16)(u1.z * dv);
        h[7] = (_Float16)(u1.w * dv);
      }
      *(f16x8*)((char*)Ah + swz(c * 16)) = h;
    }
  } else {
    const _Float16* A = (const _Float16*)Ain;
    for (int c = t; c < 2048; c += 256) {
      int r = c >> 4;
      int row = rbase + r;
      f16x8 h = {};
      if (row < M) h = *(const f16x8*)(A + (size_t)row * 128 + (c & 15) * 8);
      *(f16x8*)((char*)Ah + swz(c * 16)) = h;
    }
  }
  __syncthreads();

  const int wave = t >> 6, lane = t & 63;
  const int l16 = lane & 15, lk = lane >> 4;

  f32x4 acc[2][NB];
#pragma unroll
  for (int m = 0; m < 2; ++m)
#pragma unroll
    for (int n = 0; n < NB; ++n) acc[m][n] = (f32x4){0.f, 0.f, 0.f, 0.f};

#pragma unroll
  for (int ks = 0; ks < 4; ++ks) {
    const int kbyte = ks * 64 + lk * 16;  // (ks*32 + lk*8) halves
    f16x8 afr[2];
#pragma unroll
    for (int m = 0; m < 2; ++m) {
      int row = wave * 32 + m * 16 + l16;
      afr[m] = *(const f16x8*)((const char*)Ah + swz(row * 256 + kbyte));
    }
#pragma unroll
    for (int n = 0; n < NB; ++n) {
      int wrow = n * 16 + l16;
      f16x8 wfr = *(const f16x8*)((const char*)Wt + swz(wrow * 256 + kbyte));
#pragma unroll
      for (int m = 0; m < 2; ++m)
        acc[m][n] = __builtin_amdgcn_mfma_f32_16x16x32_f16(wfr, afr[m], acc[m][n], 0, 0, 0);
    }
  }

  // epilogue: C[row][col], row = rbase+wave*32+m*16+l16, col = n*16+lk*4+r
#pragma unroll
  for (int m = 0; m < 2; ++m) {
    int row = rbase + wave * 32 + m * 16 + l16;
    if (row < M) {
      _Float16* yr = Y + (size_t)row * BN + lk * 4;
#pragma unroll
      for (int n = 0; n < NB; ++n) {
        f16x4 h = {(_Float16)acc[m][n][0], (_Float16)acc[m][n][1],
                   (_Float16)acc[m][n][2], (_Float16)acc[m][n][3]};
        *(f16x4*)(yr + n * 16) = h;
      }
    }
  }
}

// ---------------- aggregation (fp16 y, wave-uniform control flow) ------------
// D=128 layers 1-2: writes h' = fp16(dinv * relu(dinv*sum + b)) (pre-scaled).
__global__ __launch_bounds__(256) void k_agg128h(const _Float16* __restrict__ Y,
                                                 const int* __restrict__ rowptr,
                                                 const int* __restrict__ srcs,
                                                 const float* __restrict__ dinv,
                                                 const float* __restrict__ bias,
                                                 _Float16* __restrict__ Out, int n) {
  const int wave = threadIdx.x >> 6;
  const int lane = threadIdx.x & 63;
  const int node = blockIdx.x * 4 + wave;
  if (node >= n) return;
  const int part = lane >> 4;  // which edge of the quad (0..3)
  const int q = lane & 15;     // element block: cols q*8..q*8+7
  const int jb = rowptr[node];
  const int je = rowptr[node + 1];

  float acc[8];
#pragma unroll
  for (int j = 0; j < 8; ++j) acc[j] = 0.f;
  if (part == 0) {  // self loop
    half8 s = *(const half8*)(Y + (size_t)node * 128 + q * 8);
#pragma unroll
    for (int j = 0; j < 8; ++j) acc[j] = (float)s[j];
  }

  for (int j0 = jb; j0 < je; j0 += 64) {
    const int m = min(64, je - j0);  // wave-uniform
    int idx = 0;
    if (lane < m) idx = srcs[j0 + lane];
    const int full = m & ~15;  // wave-uniform
    int eb = 0;
    for (; eb < full; eb += 16) {  // uniform trip count
      const int e0 = eb + part;
      int s0 = __shfl(idx, e0);
      int s1 = __shfl(idx, e0 + 4);
      int s2 = __shfl(idx, e0 + 8);
      int s3 = __shfl(idx, e0 + 12);
      half8 v0 = *(const half8*)(Y + (size_t)s0 * 128 + q * 8);
      half8 v1 = *(const half8*)(Y + (size_t)s1 * 128 + q * 8);
      half8 v2 = *(const half8*)(Y + (size_t)s2 * 128 + q * 8);
      half8 v3 = *(const half8*)(Y + (size_t)s3 * 128 + q * 8);
#pragma unroll
      for (int j = 0; j < 8; ++j)
        acc[j] += ((float)v0[j] + (float)v1[j]) + ((float)v2[j] + (float)v3[j]);
    }
    if (eb < m) {  // ONE masked tail iteration, all lanes active at shfls
      const int e0 = eb + part;
      int s0 = __shfl(idx, e0);
      int s1 = __shfl(idx, e0 + 4);
      int s2 = __shfl(idx, e0 + 8);
      int s3 = __shfl(idx, e0 + 12);
      half8 v0 = *(const half8*)(Y + (size_t)s0 * 128 + q * 8);
      half8 v1 = *(const half8*)(Y + (size_t)s1 * 128 + q * 8);
      half8 v2 = *(const half8*)(Y + (size_t)s2 * 128 + q * 8);
      half8 v3 = *(const half8*)(Y + (size_t)s3 * 128 + q * 8);
      const float m0 = (e0 < m) ? 1.f : 0.f;
      const float m1 = (e0 + 4 < m) ? 1.f : 0.f;
      const float m2 = (e0 + 8 < m) ? 1.f : 0.f;
      const float m3 = (e0 + 12 < m) ? 1.f : 0.f;
#pragma unroll
      for (int j = 0; j < 8; ++j)
        acc[j] += (m0 * (float)v0[j] + m1 * (float)v1[j]) +
                  (m2 * (float)v2[j] + m3 * (float)v3[j]);
    }
  }

#pragma unroll
  for (int j = 0; j < 8; ++j) {
    acc[j] += __shfl_xor(acc[j], 16);
    acc[j] += __shfl_xor(acc[j], 32);
  }

  if (part == 0) {
    const float dv = dinv[node];
    f16x8 h;
#pragma unroll
    for (int j = 0; j < 8; ++j) {
      float o = fmaf(acc[j], dv, bias[q * 8 + j]);
      o = fmaxf(o, 0.f);
      h[j] = (_Float16)(o * dv);  // pre-scale for next layer's GEMM
    }
    *(f16x8*)(Out + (size_t)node * 128 + q * 8) = h;
  }
}

// D=64 final layer: fp32 out, bias, no relu, no prescale.
__global__ __launch_bounds__(256) void k_agg64h(const _Float16* __restrict__ Y,
                                                const int* __restrict__ rowptr,
                                                const int* __restrict__ srcs,
                                                const float* __restrict__ dinv,
                                                const float* __restrict__ bias,
                                                float* __restrict__ Out, int n) {
  const int wave = threadIdx.x >> 6;
  const int lane = threadIdx.x & 63;
  const int node = blockIdx.x * 4 + wave;
  if (node >= n) return;
  const int part = lane >> 3;  // which edge of the octet (0..7)
  const int q = lane & 7;      // element block: cols q*8..q*8+7
  const int jb = rowptr[node];
  const int je = rowptr[node + 1];

  float acc[8];
#pragma unroll
  for (int j = 0; j < 8; ++j) acc[j] = 0.f;
  if (part == 0) {  // self loop
    half8 s = *(const half8*)(Y + (size_t)node * 64 + q * 8);
#pragma unroll
    for (int j = 0; j < 8; ++j) acc[j] = (float)s[j];
  }

  for (int j0 = jb; j0 < je; j0 += 64) {
    const int m = min(64, je - j0);  // wave-uniform
    int idx = 0;
    if (lane < m) idx = srcs[j0 + lane];
    const int full = m & ~31;  // wave-uniform
    int eb = 0;
    for (; eb < full; eb += 32) {
      const int e0 = eb + part;
      int s0 = __shfl(idx, e0);
      int s1 = __shfl(idx, e0 + 8);
      int s2 = __shfl(idx, e0 + 16);
      int s3 = __shfl(idx, e0 + 24);
      half8 v0 = *(const half8*)(Y + (size_t)s0 * 64 + q * 8);
      half8 v1 = *(const half8*)(Y + (size_t)s1 * 64 + q * 8);
      half8 v2 = *(const half8*)(Y + (size_t)s2 * 64 + q * 8);
      half8 v3 = *(const half8*)(Y + (size_t)s3 * 64 + q * 8);
#pragma unroll
      for (int j = 0; j < 8; ++j)
        acc[j] += ((float)v0[j] + (float)v1[j]) + ((float)v2[j] + (float)v3[j]);
    }
    if (eb < m) {  // one masked tail iteration
      const int e0 = eb + part;
      int s0 = __shfl(idx, e0);
      int s1 = __shfl(idx, e0 + 8);
      int s2 = __shfl(idx, e0 + 16);
      int s3 = __shfl(idx, e0 + 24);
      half8 v0 = *(const half8*)(Y + (size_t)s0 * 64 + q * 8);
      half8 v1 = *(const half8*)(Y + (size_t)s1 * 64 + q * 8);
      half8 v2 = *(const half8*)(Y + (size_t)s2 * 64 + q * 8);
      half8 v3 = *(const half8*)(Y + (size_t)s3 * 64 + q * 8);
      const float m0 = (e0 < m) ? 1.f : 0.f;
      const float m1 = (e0 + 8 < m) ? 1.f : 0.f;
      const float m2 = (e0 + 16 < m) ? 1.f : 0.f;
      const float m3 = (e0 + 24 < m) ? 1.f : 0.f;
#pragma unroll
      for (int j = 0; j < 8; ++j)
        acc[j] += (m0 * (float)v0[j] + m1 * (float)v1[j]) +
                  (m2 * (float)v2[j] + m3 * (float)v3[j]);
    }
  }

#pragma unroll
  for (int j = 0; j < 8; ++j) {
    acc[j] += __shfl_xor(acc[j], 8);
    acc[j] += __shfl_xor(acc[j], 16);
    acc[j] += __shfl_xor(acc[j], 32);
  }

  if (part == 0) {
    const float dv = dinv[node];
    float o[8];
#pragma unroll
    for (int j = 0; j < 8; ++j) o[j] = fmaf(acc[j], dv, bias[q * 8 + j]);
    float* orow = Out + (size_t)node * 64 + q * 8;
    *(float4*)(orow) = make_float4(o[0], o[1], o[2], o[3]);
    *(float4*)(orow + 4) = make_float4(o[4], o[5], o[6], o[7]);
  }
}

// ---------------- launch ----------------

extern "C" void kernel_launch(void* const* d_in, const int* in_sizes, int n_in,
                              void* d_out, int out_size, void* d_ws, size_t ws_size,
                              hipStream_t stream) {
  const float* x = (const float*)d_in[0];
  const int* ei = (const int*)d_in[1];
  const float* W1 = (const float*)d_in[2];
  const float* b1 = (const float*)d_in[3];
  const float* W2 = (const float*)d_in[4];
  const float* b2 = (const float*)d_in[5];
  const float* W3 = (const float*)d_in[6];
  const float* b3 = (const float*)d_in[7];
  float* out = (float*)d_out;

  const int* erow = ei;       // edge_index[0] = sources
  const int* ecol = ei + NE;  // edge_index[1] = targets

  char* w = (char*)d_ws;
  auto alloc = [&](size_t b) {
    char* p = w;
    w += (b + 255) & ~(size_t)255;
    return (void*)p;
  };
  float* dinv = (float*)alloc((size_t)NN * 4);
  int* rowptr = (int*)alloc((size_t)(NN + 1) * 4);
  int* bcnt = (int*)alloc((size_t)(G + 1) * 4);
  int* bbase = (int*)alloc((size_t)(G + 1) * 4);
  int* cursor = (int*)alloc((size_t)G * 4);
  int* srcs = (int*)alloc((size_t)NE * 4);
  _Float16* w1h = (_Float16*)alloc((size_t)128 * 128 * 2);
  _Float16* w2h = (_Float16*)alloc((size_t)128 * 128 * 2);
  _Float16* w3h = (_Float16*)alloc((size_t)128 * 64 * 2);
  _Float16* ybuf = (_Float16*)alloc((size_t)NN * 128 * 2);  // fp16 y
  _Float16* hbuf = (_Float16*)alloc((size_t)NN * 128 * 2);  // fp16 h'
  // temp edge pairs (12.8 MB) alias ybuf (25.6 MB, dead until first GEMM)
  unsigned long long* temp = (unsigned long long*)ybuf;

  // preprocessing: bucketed counting sort -> rowptr, srcs, dinv
  k_zero<<<(G + 255) / 256, 256, 0, stream>>>(bcnt, G);
  k_bhist<<<NCH, 256, 0, stream>>>(ecol, bcnt);
  k_bscan<<<1, 256, 0, stream>>>(bcnt, bbase, cursor);
  k_bucket<<<NCH, 256, 0, stream>>>(erow, ecol, cursor, temp);
  k_group<<<G, 256, 0, stream>>>(temp, bbase, rowptr, dinv, srcs);

  // weights -> fp16 transposed
  k_wconv<<<64, 256, 0, stream>>>(W1, w1h, 128);
  k_wconv<<<64, 256, 0, stream>>>(W2, w2h, 128);
  k_wconv<<<32, 256, 0, stream>>>(W3, w3h, 64);

  const int nbG = (NN + 127) / 128;  // 782
  const int nbA = (NN + 3) / 4;      // 25000

  // Layer 1: y1 = (dinv*x) @ W1  -> agg -> hbuf (fp16 pre-scaled)
  k_gemm_mfma<128, true><<<nbG, 256, 0, stream>>>(x, w1h, dinv, ybuf, NN);
  k_agg128h<<<nbA, 256, 0, stream>>>(ybuf, rowptr, srcs, dinv, b1, hbuf, NN);
  // Layer 2
  k_gemm_mfma<128, false><<<nbG, 256, 0, stream>>>(hbuf, w2h, dinv, ybuf, NN);
  k_agg128h<<<nbA, 256, 0, stream>>>(ybuf, rowptr, srcs, dinv, b2, hbuf, NN);
  // Layer 3: fp32 output
  k_gemm_mfma<64, false><<<nbG, 256, 0, stream>>>(hbuf, w3h, dinv, ybuf, NN);
  k_agg64h<<<nbA, 256, 0, stream>>>(ybuf, rowptr, srcs, dinv, b3, out, NN);
}

// Round 7
// 267.852 us; speedup vs baseline: 2.6270x; 1.0627x over previous
//
#include <hip/hip_runtime.h>

#define NN 100000
#define NE 1600000
constexpr int KDIM = 128;
constexpr int NPB = 128;                  // nodes per bucket (col>>7)
constexpr int G = (NN + NPB - 1) / NPB;   // 782 buckets
constexpr int CH = 8192;                  // edges per chunk
constexpr int NCH = (NE + CH - 1) / CH;   // 196 chunks
constexpr int CAP = 4000;                 // padded bucket capacity (mean 2046, sigma 45)

typedef _Float16 f16x4 __attribute__((ext_vector_type(4)));
typedef _Float16 f16x8 __attribute__((ext_vector_type(8)));
typedef float f32x4 __attribute__((ext_vector_type(4)));
using half8 = f16x8;

// LDS XOR swizzle for 256B-row-stride b128 access: spreads bank slots
__device__ __forceinline__ int swz(int byte) {
  return byte ^ (((byte >> 8) & 7) << 4);
}

// ---------------- preprocessing: bucketed counting sort (padded) -------------

__global__ __launch_bounds__(256) void k_zero(int* p, int n) {
  int i = blockIdx.x * 256 + threadIdx.x;
  if (i < n) p[i] = 0;
}

// bin edges into padded bucket regions: LDS hist + bulk reservation + append
__global__ __launch_bounds__(256) void k_bucketP(const int* __restrict__ row,
                                                 const int* __restrict__ col,
                                                 int* __restrict__ cursor,
                                                 unsigned long long* __restrict__ temp) {
  __shared__ int h[G];
  for (int i = threadIdx.x; i < G; i += 256) h[i] = 0;
  __syncthreads();
  const int base = blockIdx.x * CH;
  const int m = min(CH, NE - base);
  for (int i = threadIdx.x; i < m; i += 256) atomicAdd(&h[col[base + i] >> 7], 1);
  __syncthreads();
  for (int i = threadIdx.x; i < G; i += 256) {
    int c = h[i];
    if (c) h[i] = atomicAdd(&cursor[i], c);  // h[i] becomes this WG's local base
  }
  __syncthreads();
  for (int i = threadIdx.x; i < m; i += 256) {
    int cc = col[base + i];
    int rr = row[base + i];
    int slot = atomicAdd(&h[cc >> 7], 1);
    temp[(size_t)(cc >> 7) * CAP + slot] =
        ((unsigned long long)(unsigned)cc << 32) | (unsigned)rr;
  }
}

// exclusive scan of bucket counts (in cursor) -> bbase[0..G]
__global__ void k_bscan(const int* __restrict__ cnt, int* __restrict__ bbase) {
  __shared__ int sd[256];
  const int t = threadIdx.x;
  int v[4];
  int s = 0;
#pragma unroll
  for (int j = 0; j < 4; ++j) {
    int idx = t * 4 + j;
    v[j] = (idx < G) ? cnt[idx] : 0;
    s += v[j];
  }
  sd[t] = s;
  __syncthreads();
  for (int off = 1; off < 256; off <<= 1) {
    int x = (t >= off) ? sd[t - off] : 0;
    __syncthreads();
    sd[t] += x;
    __syncthreads();
  }
  int run = sd[t] - s;  // exclusive prefix
#pragma unroll
  for (int j = 0; j < 4; ++j) {
    int idx = t * 4 + j;
    if (idx < G) bbase[idx] = run;
    run += v[j];
  }
  if (t == 255) bbase[G] = run;  // == NE
}

// per-bucket: LDS node hist -> scan -> rowptr/dinv, then group srcs (CSR)
__global__ __launch_bounds__(256) void k_groupP(const unsigned long long* __restrict__ temp,
                                                const int* __restrict__ bbase,
                                                int* __restrict__ rowptr,
                                                float* __restrict__ dinv,
                                                int* __restrict__ srcs) {
  __shared__ int fill[NPB];
  __shared__ int nbase[NPB];
  __shared__ int sc[NPB];
  const int g = blockIdx.x, t = threadIdx.x;
  const int lo = g * NPB;
  const int b0 = bbase[g];
  const int n = bbase[g + 1] - b0;
  const unsigned long long* tp = temp + (size_t)g * CAP;
  if (t < NPB) fill[t] = 0;
  __syncthreads();
  for (int s = t; s < n; s += 256) {
    int cc = (int)(tp[s] >> 32);
    atomicAdd(&fill[cc & (NPB - 1)], 1);
  }
  __syncthreads();
  int v = 0;
  if (t < NPB) {
    v = fill[t];
    sc[t] = v;
  }
  __syncthreads();
  for (int off = 1; off < NPB; off <<= 1) {
    int x = 0;
    if (t < NPB && t >= off) x = sc[t - off];
    __syncthreads();
    if (t < NPB) sc[t] += x;
    __syncthreads();
  }
  if (t < NPB) {
    int excl = sc[t] - v;
    nbase[t] = b0 + excl;
    int node = lo + t;
    if (node < NN) {
      rowptr[node] = b0 + excl;
      dinv[node] = rsqrtf((float)(v + 1));  // +1 self loop
    }
    fill[t] = 0;
  }
  if (g == G - 1 && t == 0) rowptr[NN] = NE;
  __syncthreads();
  for (int s = t; s < n; s += 256) {
    unsigned long long p = tp[s];
    int cc = (int)(p >> 32);
    int rr = (int)(unsigned)(p & 0xffffffffull);
    int c = cc & (NPB - 1);
    int slot = atomicAdd(&fill[c], 1);
    srcs[nbase[c] + slot] = rr;
  }
}

// -------- weight convert (all 3): W fp32 [128][N] -> Wt fp16 [N][128] --------
__global__ __launch_bounds__(256) void k_wconvAll(const float* __restrict__ W1,
                                                  const float* __restrict__ W2,
                                                  const float* __restrict__ W3,
                                                  _Float16* __restrict__ w1h,
                                                  _Float16* __restrict__ w2h,
                                                  _Float16* __restrict__ w3h) {
  int i = blockIdx.x * 256 + threadIdx.x;
  if (i < 16384) {
    int k = i >> 7, c = i & 127;
    w1h[c * 128 + k] = (_Float16)W1[i];
  } else if (i < 32768) {
    int j = i - 16384;
    int k = j >> 7, c = j & 127;
    w2h[c * 128 + k] = (_Float16)W2[j];
  } else if (i < 40960) {
    int j = i - 32768;
    int k = j >> 6, c = j & 63;
    w3h[c * 128 + k] = (_Float16)W3[j];
  }
}

// ---------------- MFMA GEMM: Y = A @ W, fp16 in/out, fp32 accumulate --------
// Row M (== NN) of Y is written with ZEROS (dummy row for agg's unified tail).
template <int BN, bool F32IN>
__global__ __launch_bounds__(256, 2) void k_gemm_mfma(const void* __restrict__ Ain,
                                                      const _Float16* __restrict__ Wt_g,
                                                      const float* __restrict__ dinv,
                                                      _Float16* __restrict__ Y, int M) {
  constexpr int NB = BN / 16;
  __shared__ _Float16 Ah[128 * 128];  // 32 KB, swizzled rows of 256 B
  __shared__ _Float16 Wt[BN * 128];   // 32/16 KB, swizzled
  const int t = threadIdx.x;
  const int rbase = blockIdx.x * 128;

  for (int c = t; c < BN * 16; c += 256) {
    f16x8 v = *(const f16x8*)((const char*)Wt_g + c * 16);
    *(f16x8*)((char*)Wt + swz(c * 16)) = v;
  }
  if constexpr (F32IN) {
    const float* A = (const float*)Ain;
    for (int c = t; c < 2048; c += 256) {
      int r = c >> 4, kc = c & 15;
      int row = rbase + r;
      f16x8 h = {};
      if (row < M) {
        float dv = dinv[row];
        const float* p = A + (size_t)row * 128 + kc * 8;
        float4 u0 = *(const float4*)p;
        float4 u1 = *(const float4*)(p + 4);
        h[0] = (_Float16)(u0.x * dv);
        h[1] = (_Float16)(u0.y * dv);
        h[2] = (_Float16)(u0.z * dv);
        h[3] = (_Float16)(u0.w * dv);
        h[4] = (_Float16)(u1.x * dv);
        h[5] = (_Float16)(u1.y * dv);
        h[6] = (_Float16)(u1.z * dv);
        h[7] = (_Float16)(u1.w * dv);
      }
      *(f16x8*)((char*)Ah + swz(c * 16)) = h;
    }
  } else {
    const _Float16* A = (const _Float16*)Ain;
    for (int c = t; c < 2048; c += 256) {
      int r = c >> 4;
      int row = rbase + r;
      f16x8 h = {};
      if (row < M) h = *(const f16x8*)(A + (size_t)row * 128 + (c & 15) * 8);
      *(f16x8*)((char*)Ah + swz(c * 16)) = h;
    }
  }
  __syncthreads();

  const int wave = t >> 6, lane = t & 63;
  const int l16 = lane & 15, lk = lane >> 4;

  f32x4 acc[2][NB];
#pragma unroll
  for (int mm = 0; mm < 2; ++mm)
#pragma unroll
    for (int n = 0; n < NB; ++n) acc[mm][n] = (f32x4){0.f, 0.f, 0.f, 0.f};

#pragma unroll
  for (int ks = 0; ks < 4; ++ks) {
    const int kbyte = ks * 64 + lk * 16;
    f16x8 afr[2];
#pragma unroll
    for (int mm = 0; mm < 2; ++mm) {
      int row = wave * 32 + mm * 16 + l16;
      afr[mm] = *(const f16x8*)((const char*)Ah + swz(row * 256 + kbyte));
    }
#pragma unroll
    for (int n = 0; n < NB; ++n) {
      int wrow = n * 16 + l16;
      f16x8 wfr = *(const f16x8*)((const char*)Wt + swz(wrow * 256 + kbyte));
#pragma unroll
      for (int mm = 0; mm < 2; ++mm)
        acc[mm][n] = __builtin_amdgcn_mfma_f32_16x16x32_f16(wfr, afr[mm], acc[mm][n], 0, 0, 0);
    }
  }

#pragma unroll
  for (int mm = 0; mm < 2; ++mm) {
    int row = rbase + wave * 32 + mm * 16 + l16;
    if (row < M) {
      _Float16* yr = Y + (size_t)row * BN + lk * 4;
#pragma unroll
      for (int n = 0; n < NB; ++n) {
        f16x4 h = {(_Float16)acc[mm][n][0], (_Float16)acc[mm][n][1],
                   (_Float16)acc[mm][n][2], (_Float16)acc[mm][n][3]};
        *(f16x4*)(yr + n * 16) = h;
      }
    } else if (row == M) {  // zero dummy row for agg's unified tail
      _Float16* yr = Y + (size_t)row * BN + lk * 4;
      f16x4 z = {};
#pragma unroll
      for (int n = 0; n < NB; ++n) *(f16x4*)(yr + n * 16) = z;
    }
  }
}

// ---------------- aggregation (fp16 tree, unified tail via zero row) ---------
// Invalid lanes carry idx=NN -> gather the zeroed dummy row: no masks, no
// divergence (round-3 lesson: all shfl sources stay active).
__global__ __launch_bounds__(256) void k_agg128h(const _Float16* __restrict__ Y,
                                                 const int* __restrict__ rowptr,
                                                 const int* __restrict__ srcs,
                                                 const float* __restrict__ dinv,
                                                 const float* __restrict__ bias,
                                                 _Float16* __restrict__ Out, int n) {
  const int wave = threadIdx.x >> 6;
  const int lane = threadIdx.x & 63;
  const int node = blockIdx.x * 4 + wave;
  if (node >= n) return;
  const int part = lane >> 4;  // which edge of the quad (0..3)
  const int q = lane & 15;     // element block: cols q*8..q*8+7
  const int jb = rowptr[node];
  const int je = rowptr[node + 1];

  float acc[8];
#pragma unroll
  for (int j = 0; j < 8; ++j) acc[j] = 0.f;
  if (part == 0) {  // self loop
    half8 s = *(const half8*)(Y + (size_t)node * 128 + q * 8);
#pragma unroll
    for (int j = 0; j < 8; ++j) acc[j] = (float)s[j];
  }

  for (int j0 = jb; j0 < je; j0 += 64) {
    const int m = min(64, je - j0);  // wave-uniform
    const int idx = (lane < m) ? srcs[j0 + lane] : NN;  // NN = zero row
    for (int eb = 0; eb < m; eb += 16) {  // uniform trip count, no tail branch
      const int e0 = eb + part;
      int s0 = __shfl(idx, e0);
      int s1 = __shfl(idx, e0 + 4);
      int s2 = __shfl(idx, e0 + 8);
      int s3 = __shfl(idx, e0 + 12);
      half8 v0 = *(const half8*)(Y + (size_t)s0 * 128 + q * 8);
      half8 v1 = *(const half8*)(Y + (size_t)s1 * 128 + q * 8);
      half8 v2 = *(const half8*)(Y + (size_t)s2 * 128 + q * 8);
      half8 v3 = *(const half8*)(Y + (size_t)s3 * 128 + q * 8);
      half8 s = (v0 + v1) + (v2 + v3);  // fp16 pairwise tree (v_pk_add_f16)
#pragma unroll
      for (int j = 0; j < 8; ++j) acc[j] += (float)s[j];
    }
  }

#pragma unroll
  for (int j = 0; j < 8; ++j) {
    acc[j] += __shfl_xor(acc[j], 16);
    acc[j] += __shfl_xor(acc[j], 32);
  }

  if (part == 0) {
    const float dv = dinv[node];
    f16x8 h;
#pragma unroll
    for (int j = 0; j < 8; ++j) {
      float o = fmaf(acc[j], dv, bias[q * 8 + j]);
      o = fmaxf(o, 0.f);
      h[j] = (_Float16)(o * dv);  // pre-scale for next layer's GEMM
    }
    *(f16x8*)(Out + (size_t)node * 128 + q * 8) = h;
  }
}

// D=64 final layer: fp32 out, bias, no relu, no prescale.
__global__ __launch_bounds__(256) void k_agg64h(const _Float16* __restrict__ Y,
                                                const int* __restrict__ rowptr,
                                                const int* __restrict__ srcs,
                                                const float* __restrict__ dinv,
                                                const float* __restrict__ bias,
                                                float* __restrict__ Out, int n) {
  const int wave = threadIdx.x >> 6;
  const int lane = threadIdx.x & 63;
  const int node = blockIdx.x * 4 + wave;
  if (node >= n) return;
  const int part = lane >> 3;  // which edge of the octet (0..7)
  const int q = lane & 7;      // element block: cols q*8..q*8+7
  const int jb = rowptr[node];
  const int je = rowptr[node + 1];

  float acc[8];
#pragma unroll
  for (int j = 0; j < 8; ++j) acc[j] = 0.f;
  if (part == 0) {  // self loop
    half8 s = *(const half8*)(Y + (size_t)node * 64 + q * 8);
#pragma unroll
    for (int j = 0; j < 8; ++j) acc[j] = (float)s[j];
  }

  for (int j0 = jb; j0 < je; j0 += 64) {
    const int m = min(64, je - j0);  // wave-uniform
    const int idx = (lane < m) ? srcs[j0 + lane] : NN;  // NN = zero row
    for (int eb = 0; eb < m; eb += 32) {  // uniform, no tail branch
      const int e0 = eb + part;
      int s0 = __shfl(idx, e0);
      int s1 = __shfl(idx, e0 + 8);
      int s2 = __shfl(idx, e0 + 16);
      int s3 = __shfl(idx, e0 + 24);
      half8 v0 = *(const half8*)(Y + (size_t)s0 * 64 + q * 8);
      half8 v1 = *(const half8*)(Y + (size_t)s1 * 64 + q * 8);
      half8 v2 = *(const half8*)(Y + (size_t)s2 * 64 + q * 8);
      half8 v3 = *(const half8*)(Y + (size_t)s3 * 64 + q * 8);
      half8 s = (v0 + v1) + (v2 + v3);
#pragma unroll
      for (int j = 0; j < 8; ++j) acc[j] += (float)s[j];
    }
  }

#pragma unroll
  for (int j = 0; j < 8; ++j) {
    acc[j] += __shfl_xor(acc[j], 8);
    acc[j] += __shfl_xor(acc[j], 16);
    acc[j] += __shfl_xor(acc[j], 32);
  }

  if (part == 0) {
    const float dv = dinv[node];
    float o[8];
#pragma unroll
    for (int j = 0; j < 8; ++j) o[j] = fmaf(acc[j], dv, bias[q * 8 + j]);
    float* orow = Out + (size_t)node * 64 + q * 8;
    *(float4*)(orow) = make_float4(o[0], o[1], o[2], o[3]);
    *(float4*)(orow + 4) = make_float4(o[4], o[5], o[6], o[7]);
  }
}

// ---------------- launch ----------------

extern "C" void kernel_launch(void* const* d_in, const int* in_sizes, int n_in,
                              void* d_out, int out_size, void* d_ws, size_t ws_size,
                              hipStream_t stream) {
  const float* x = (const float*)d_in[0];
  const int* ei = (const int*)d_in[1];
  const float* W1 = (const float*)d_in[2];
  const float* b1 = (const float*)d_in[3];
  const float* W2 = (const float*)d_in[4];
  const float* b2 = (const float*)d_in[5];
  const float* W3 = (const float*)d_in[6];
  const float* b3 = (const float*)d_in[7];
  float* out = (float*)d_out;

  const int* erow = ei;       // edge_index[0] = sources
  const int* ecol = ei + NE;  // edge_index[1] = targets

  char* w = (char*)d_ws;
  auto alloc = [&](size_t b) {
    char* p = w;
    w += (b + 255) & ~(size_t)255;
    return (void*)p;
  };
  float* dinv = (float*)alloc((size_t)NN * 4);
  int* rowptr = (int*)alloc((size_t)(NN + 1) * 4);
  int* cursor = (int*)alloc((size_t)G * 4);
  int* bbase = (int*)alloc((size_t)(G + 1) * 4);
  int* srcs = (int*)alloc((size_t)NE * 4);
  _Float16* w1h = (_Float16*)alloc((size_t)128 * 128 * 2);
  _Float16* w2h = (_Float16*)alloc((size_t)128 * 128 * 2);
  _Float16* w3h = (_Float16*)alloc((size_t)128 * 64 * 2);
  _Float16* ybuf = (_Float16*)alloc((size_t)(NN + 1) * 128 * 2);  // +1 zero row
  _Float16* hbuf = (_Float16*)alloc((size_t)(NN + 1) * 128 * 2);
  // temp edge pairs (25.02 MB) alias ybuf (25.6 MB, dead until first GEMM)
  unsigned long long* temp = (unsigned long long*)ybuf;

  // preprocessing: padded bucketed counting sort -> rowptr, srcs, dinv
  k_zero<<<(G + 255) / 256, 256, 0, stream>>>(cursor, G);
  k_bucketP<<<NCH, 256, 0, stream>>>(erow, ecol, cursor, temp);
  k_bscan<<<1, 256, 0, stream>>>(cursor, bbase);
  k_groupP<<<G, 256, 0, stream>>>(temp, bbase, rowptr, dinv, srcs);
  k_wconvAll<<<160, 256, 0, stream>>>(W1, W2, W3, w1h, w2h, w3h);

  const int nbG = (NN + 127) / 128;  // 782 (covers dummy row NN)
  const int nbA = (NN + 3) / 4;      // 25000

  // Layer 1: y1 = (dinv*x) @ W1  -> agg -> hbuf (fp16 pre-scaled)
  k_gemm_mfma<128, true><<<nbG, 256, 0, stream>>>(x, w1h, dinv, ybuf, NN);
  k_agg128h<<<nbA, 256, 0, stream>>>(ybuf, rowptr, srcs, dinv, b1, hbuf, NN);
  // Layer 2
  k_gemm_mfma<128, false><<<nbG, 256, 0, stream>>>(hbuf, w2h, dinv, ybuf, NN);
  k_agg128h<<<nbA, 256, 0, stream>>>(ybuf, rowptr, srcs, dinv, b2, hbuf, NN);
  // Layer 3: fp32 output
  k_gemm_mfma<64, false><<<nbG, 256, 0, stream>>>(hbuf, w3h, dinv, ybuf, NN);
  k_agg64h<<<nbA, 256, 0, stream>>>(ybuf, rowptr, srcs, dinv, b3, out, NN);
}